// Round 5
// baseline (5390.801 us; speedup 1.0000x reference)
//
#include <hip/hip_runtime.h>
#include <hip/hip_bf16.h>
#include <math.h>

#define D_MODEL 384
#define D_INNER 768
#define D_STATE 16
#define DT_RANK 24
#define NXP 56          // DT_RANK + 2*D_STATE
#define LTOK 196
#define BSZ 16
#define NROW 3136       // BSZ * LTOK
#define NDEPTH 24
#define NCLS 1000

constexpr float kSqrtC   = 0.70710678118654752440f;
constexpr float kMaxNorm = 0.95f / 0.70710678118654752440f;   // 1.3435029...

typedef unsigned short u16;
typedef short  bf16x8 __attribute__((ext_vector_type(8)));
typedef u16    u16x8  __attribute__((ext_vector_type(8)));
typedef float  f32x4  __attribute__((ext_vector_type(4)));

__device__ __forceinline__ float clampf(float x, float lo, float hi) {
  return fminf(fmaxf(x, lo), hi);
}

// f32 -> bf16 (RNE)
__device__ __forceinline__ u16 f2bf(float f) {
  union { float f; unsigned u; } v; v.f = f;
  return (u16)((v.u + 0x7FFFu + ((v.u >> 16) & 1u)) >> 16);
}
// bf16 -> f32
__device__ __forceinline__ float bf2f(u16 s) {
  union { unsigned u; float f; } v; v.u = ((unsigned)s) << 16;
  return v.f;
}

// 64-lane wave reduction (no LDS, no barriers)
__device__ __forceinline__ float waveSum(float v) {
#pragma unroll
  for (int o = 1; o < 64; o <<= 1) v += __shfl_xor(v, o, 64);
  return v;
}

// block=128 sum-reduce with broadcast (stem kernels only).
__device__ __forceinline__ float blockSum128(float v, float* sm) {
#pragma unroll
  for (int o = 32; o > 0; o >>= 1) v += __shfl_down(v, o, 64);
  __syncthreads();
  if ((threadIdx.x & 63) == 0) sm[threadIdx.x >> 6] = v;
  __syncthreads();
  return sm[0] + sm[1];
}

// --------------------------- f32 -> bf16 bulk convert (weights, per call) ---
__global__ __launch_bounds__(256) void k_cvt(const float* __restrict__ s,
                                             u16* __restrict__ d, int n4) {
  int i = blockIdx.x * 256 + threadIdx.x;
  if (i >= n4) return;
  float4 v = ((const float4*)s)[i];
  short4 o = {(short)f2bf(v.x), (short)f2bf(v.y), (short)f2bf(v.z),
              (short)f2bf(v.w)};
  *(short4*)&d[(size_t)i * 4] = o;
}

// ------------------------------------------------- im2col (emit bf16) ------
__global__ __launch_bounds__(256) void k_im2col(const float* __restrict__ x,
                                                u16* __restrict__ P) {
  size_t idx = (size_t)blockIdx.x * 256 + threadIdx.x;
  if (idx >= (size_t)NROW * 768) return;
  int k = (int)(idx % 768);
  int r = (int)(idx / 768);
  int b = r / LTOK, t = r % LTOK;
  int hp = t / 14, wp = t % 14;
  int c = k / 256, rem = k % 256, i = rem / 16, j = rem % 16;
  P[idx] = f2bf(
      x[(((size_t)(b * 3 + c) * 224) + hp * 16 + i) * 224 + wp * 16 + j]);
}

// ------------------------- pure-bf16 MFMA GEMM: C = A * W^T (+bias, act) ----
// A bf16: atr==0 -> (M,K) rm stride lda; atr==1 -> stored transposed,
// A[r][k] = Abuf[k*lda + r]. W (Nv,K) bf16 rm tight. Outputs: Cn (normal
// [r][cg], stride ldc) and/or Ct (transposed [cg][r], stride ldct); null to
// skip. obf: bf16 outputs, else f32. act: 0 none, 1 softplus(+bias),
// 2 silu if cg>=768.
#define LDA 40
__global__ __launch_bounds__(256) void k_gemm_bb(
    const u16* __restrict__ A, const u16* __restrict__ W,
    const float* __restrict__ bias, void* __restrict__ Cn,
    void* __restrict__ Ct, int K, int lda, int ldc, int ldct, int Nv, int act,
    int obf, int atr) {
  __shared__ u16 As[64 * LDA];
  __shared__ u16 Ws[64 * LDA];
  const int tid = threadIdx.x;
  const int m0 = blockIdx.x * 64;
  const int n0 = blockIdx.y * 64;
  const int lane = tid & 63;
  const int wave = tid >> 6;
  const int wm = wave & 1, wn = wave >> 1;
  const int lm = lane & 15;
  const int quad = lane >> 4;
  const int srow = tid >> 2;
  const int sseg = tid & 3;

  f32x4 acc[2][2];
#pragma unroll
  for (int i = 0; i < 2; i++)
#pragma unroll
    for (int j = 0; j < 2; j++) acc[i][j] = (f32x4){0.f, 0.f, 0.f, 0.f};

  const u16* rowA = A + (size_t)(m0 + srow) * lda + sseg * 8;
  const int wrow = n0 + srow;
  const u16* rowW = W + (size_t)wrow * K + sseg * 8;
  const bool wvalid = wrow < Nv;

  for (int k0 = 0; k0 < K; k0 += 32) {
    u16x8 av = {0, 0, 0, 0, 0, 0, 0, 0}, wv = {0, 0, 0, 0, 0, 0, 0, 0};
    if (!atr) {
      if (k0 + 32 <= K) {
        av = *(const u16x8*)(rowA + k0);
      } else {
#pragma unroll
        for (int kk = 0; kk < 8; kk++) {
          int k = k0 + sseg * 8 + kk;
          if (k < K) av[kk] = rowA[k - sseg * 8];
        }
      }
    } else {
#pragma unroll
      for (int kk = 0; kk < 8; kk++) {
        int k = k0 + sseg * 8 + kk;
        if (k < K) av[kk] = A[(size_t)k * lda + m0 + srow];
      }
    }
    if (k0 + 32 <= K) {
      if (wvalid) wv = *(const u16x8*)(rowW + k0);
    } else {
#pragma unroll
      for (int kk = 0; kk < 8; kk++) {
        int k = k0 + sseg * 8 + kk;
        if (wvalid && k < K) wv[kk] = rowW[k - sseg * 8];
      }
    }
    __syncthreads();  // guard LDS reuse from previous iter's reads
    *(u16x8*)&As[srow * LDA + sseg * 8] = av;
    *(u16x8*)&Ws[srow * LDA + sseg * 8] = wv;
    __syncthreads();
    bf16x8 af[2], bfr[2];
#pragma unroll
    for (int i = 0; i < 2; i++) {
      af[i]  = *(bf16x8*)&As[(wm * 32 + i * 16 + lm) * LDA + quad * 8];
      bfr[i] = *(bf16x8*)&Ws[(wn * 32 + i * 16 + lm) * LDA + quad * 8];
    }
#pragma unroll
    for (int i = 0; i < 2; i++)
#pragma unroll
      for (int j = 0; j < 2; j++)
        acc[i][j] = __builtin_amdgcn_mfma_f32_16x16x32_bf16(af[i], bfr[j],
                                                            acc[i][j], 0, 0, 0);
  }
  // epilogue: C/D layout col=lane&15, row=quad*4+reg
#pragma unroll
  for (int i = 0; i < 2; i++) {
#pragma unroll
    for (int j = 0; j < 2; j++) {
      int cg = n0 + wn * 32 + j * 16 + lm;
      if (cg >= Nv) continue;
      float bj = bias ? bias[cg] : 0.f;
      float o[4];
      int rgb = m0 + wm * 32 + i * 16 + quad * 4;
#pragma unroll
      for (int reg = 0; reg < 4; reg++) {
        float v = acc[i][j][reg] + bj;
        if (act == 1) v = (v > 20.f) ? v : log1pf(expf(v));
        else if (act == 2 && cg >= 768) v = v / (1.f + expf(-v));
        o[reg] = v;
      }
      if (Cn) {
#pragma unroll
        for (int reg = 0; reg < 4; reg++) {
          if (obf) ((u16*)Cn)[(size_t)(rgb + reg) * ldc + cg] = f2bf(o[reg]);
          else ((float*)Cn)[(size_t)(rgb + reg) * ldc + cg] = o[reg];
        }
      }
      if (Ct) {
        if (obf) {
          short4 o4 = {(short)f2bf(o[0]), (short)f2bf(o[1]), (short)f2bf(o[2]),
                       (short)f2bf(o[3])};
          *(short4*)&((u16*)Ct)[(size_t)cg * ldct + rgb] = o4;
        } else {
          float4 o4 = {o[0], o[1], o[2], o[3]};
          *(float4*)&((float*)Ct)[(size_t)cg * ldct + rgb] = o4;
        }
      }
    }
  }
}

// ------------------ stem a: expmap0(tokens) -> bf16 h + ||h|| ---------------
__global__ __launch_bounds__(128) void k_stem_a(const float* __restrict__ tok,
                                                u16* __restrict__ hb,
                                                float* __restrict__ xn) {
  __shared__ float sm[2];
  const int r = blockIdx.x, tid = threadIdx.x;
  float v[3];
#pragma unroll
  for (int j = 0; j < 3; j++) v[j] = tok[(size_t)r * D_MODEL + tid + j * 128];
  float s = blockSum128(v[0] * v[0] + v[1] * v[1] + v[2] * v[2], sm);
  float n = sqrtf(s + 1e-15f);
  float nc = clampf(n, 1e-8f, 5.f);
  float ke = tanhf(kSqrtC * nc) / (kSqrtC * nc);
  float rn = sqrtf(ke * ke * s + 1e-15f);
  float sc = rn > kMaxNorm ? kMaxNorm / rn : 1.f;
  float kk = ke * sc;
#pragma unroll
  for (int j = 0; j < 3; j++)
    hb[(size_t)r * D_MODEL + tid + j * 128] = f2bf(kk * v[j]);
  if (tid == 0) xn[r] = fmaxf(sqrtf(kk * kk * s + 1e-15f), 1e-8f);
}

// --- stem b: mobius_matvec tail + mobius_add(hyp_b) + hyp_LN + pos + expmap -
__global__ __launch_bounds__(128) void k_stem_b(
    const float* __restrict__ mx, const float* __restrict__ xn,
    const float* __restrict__ hyp_b, const float* __restrict__ pe_g,
    const float* __restrict__ pe_b, const float* __restrict__ pos,
    float* __restrict__ outh) {
  __shared__ float sm[2];
  const int r = blockIdx.x, tid = threadIdx.x;
  const int t = r % LTOK;
  float mv[3], bv[3];
  int dd[3];
#pragma unroll
  for (int j = 0; j < 3; j++) {
    dd[j] = tid + j * 128;
    mv[j] = mx[(size_t)r * D_MODEL + dd[j]];
    bv[j] = hyp_b[dd[j]];
  }
  float smx = blockSum128(mv[0] * mv[0] + mv[1] * mv[1] + mv[2] * mv[2], sm);
  float mxn = fmaxf(sqrtf(smx + 1e-15f), 1e-8f);
  float xnv = xn[r];
  float tt = tanhf(mxn / xnv * atanhf(fminf(kSqrtC * xnv, 1.f - 1e-5f)));
  float kres = tt / (mxn * kSqrtC);
  float res[3];
#pragma unroll
  for (int j = 0; j < 3; j++) res[j] = kres * mv[j];
  float xy = blockSum128(res[0] * bv[0] + res[1] * bv[1] + res[2] * bv[2], sm);
  float y2 = blockSum128(bv[0] * bv[0] + bv[1] * bv[1] + bv[2] * bv[2], sm);
  float x2 = kres * kres * smx;
  float al = 1.f + xy + 0.5f * y2;
  float be = 1.f - 0.5f * x2;
  float den = fmaxf(1.f + xy + 0.25f * x2 * y2, 1e-15f);
  float h1[3];
#pragma unroll
  for (int j = 0; j < 3; j++) h1[j] = (al * res[j] + be * bv[j]) / den;
  float s1 = blockSum128(h1[0] * h1[0] + h1[1] * h1[1] + h1[2] * h1[2], sm);
  float n1 = sqrtf(s1 + 1e-15f);
  float nc1 = clampf(n1, 1e-8f, kMaxNorm);
  float kl = atanhf(fminf(kSqrtC * nc1, 0.95f)) / (kSqrtC * nc1);
  float tl[3];
#pragma unroll
  for (int j = 0; j < 3; j++) tl[j] = kl * h1[j];
  float mean = blockSum128(tl[0] + tl[1] + tl[2], sm) * (1.f / 384.f);
  float dv = 0.f;
#pragma unroll
  for (int j = 0; j < 3; j++) { float d = tl[j] - mean; dv += d * d; }
  float var = blockSum128(dv, sm) * (1.f / 383.f);
  float inv = 1.f / (sqrtf(var) + 1e-5f);
  float g[3];
#pragma unroll
  for (int j = 0; j < 3; j++)
    g[j] = (tl[j] - mean) * inv * pe_g[dd[j]] + pe_b[dd[j]];
  float sg = blockSum128(g[0] * g[0] + g[1] * g[1] + g[2] * g[2], sm);
  float ng = sqrtf(sg + 1e-15f);
  float nc2 = clampf(ng, 1e-8f, 5.f);
  float ke = tanhf(kSqrtC * nc2) / (kSqrtC * nc2);
  float rn = sqrtf(ke * ke * sg + 1e-15f);
  float sc = rn > kMaxNorm ? kMaxNorm / rn : 1.f;
  float kk = ke * sc;
  float s2 = kk * kk * sg;
  float n3 = sqrtf(s2 + 1e-15f);
  float nc3 = clampf(n3, 1e-8f, kMaxNorm);
  float kl2 = atanhf(fminf(kSqrtC * nc3, 0.95f)) / (kSqrtC * nc3);
  float v[3];
#pragma unroll
  for (int j = 0; j < 3; j++)
    v[j] = kl2 * kk * g[j] + pos[(size_t)t * D_MODEL + dd[j]];
  float sv = blockSum128(v[0] * v[0] + v[1] * v[1] + v[2] * v[2], sm);
  float nv = sqrtf(sv + 1e-15f);
  float nc4 = clampf(nv, 1e-8f, 5.f);
  float ke2 = tanhf(kSqrtC * nc4) / (kSqrtC * nc4);
  float rn2 = sqrtf(ke2 * ke2 * sv + 1e-15f);
  float sc2 = rn2 > kMaxNorm ? kMaxNorm / rn2 : 1.f;
#pragma unroll
  for (int j = 0; j < 3; j++)
    outh[(size_t)r * D_MODEL + dd[j]] = ke2 * sc2 * v[j];
}

// --- residual accumulate + hyp_layernorm, one wave per row (no barriers) ----
__global__ __launch_bounds__(256) void k_resln(
    const float* __restrict__ hid, const float* __restrict__ res_in,
    float* __restrict__ res_out, const float* __restrict__ g_,
    const float* __restrict__ b_, u16* __restrict__ out_bf,
    float* __restrict__ out_f, int first, int out_logmap) {
  const int lane = threadIdx.x & 63;
  const int r = blockIdx.x * 4 + (threadIdx.x >> 6);
  float v[6];
  int dd[6];
#pragma unroll
  for (int j = 0; j < 6; j++) {
    dd[j] = lane + j * 64;
    size_t idx = (size_t)r * D_MODEL + dd[j];
    v[j] = hid[idx] + (first ? 0.f : res_in[idx]);
    res_out[idx] = v[j];
  }
  float ss = 0.f;
#pragma unroll
  for (int j = 0; j < 6; j++) ss += v[j] * v[j];
  float s = waveSum(ss);
  float n = sqrtf(s + 1e-15f);
  float nc = clampf(n, 1e-8f, kMaxNorm);
  float kl = atanhf(fminf(kSqrtC * nc, 0.95f)) / (kSqrtC * nc);
  float t[6];
  float ts = 0.f;
#pragma unroll
  for (int j = 0; j < 6; j++) { t[j] = kl * v[j]; ts += t[j]; }
  float mean = waveSum(ts) * (1.f / 384.f);
  float dv = 0.f;
#pragma unroll
  for (int j = 0; j < 6; j++) { float d = t[j] - mean; dv += d * d; }
  float var = waveSum(dv) * (1.f / 383.f);
  float inv = 1.f / (sqrtf(var) + 1e-5f);
  float g[6];
  float gs = 0.f;
#pragma unroll
  for (int j = 0; j < 6; j++) {
    g[j] = (t[j] - mean) * inv * g_[dd[j]] + b_[dd[j]];
    gs += g[j] * g[j];
  }
  float sg = waveSum(gs);
  float ng = sqrtf(sg + 1e-15f);
  float nc2 = clampf(ng, 1e-8f, 5.f);
  float ke = tanhf(kSqrtC * nc2) / (kSqrtC * nc2);
  float rn = sqrtf(ke * ke * sg + 1e-15f);
  float sc = rn > kMaxNorm ? kMaxNorm / rn : 1.f;
  float kk = ke * sc;
  if (!out_logmap) {
#pragma unroll
    for (int j = 0; j < 6; j++)
      out_bf[(size_t)r * D_MODEL + dd[j]] = f2bf(kk * g[j]);
  } else {
    float s2 = kk * kk * sg;
    float n3 = sqrtf(s2 + 1e-15f);
    float nc3 = clampf(n3, 1e-8f, kMaxNorm);
    float kl2 = atanhf(fminf(kSqrtC * nc3, 0.95f)) / (kSqrtC * nc3);
#pragma unroll
    for (int j = 0; j < 6; j++)
      out_f[(size_t)r * D_MODEL + dd[j]] = kl2 * kk * g[j];
  }
}

// ----- conv1d(k=4, causal) + SiLU, tiled; writes u transposed [d][b*L+l] ----
__global__ __launch_bounds__(256) void k_convt(const u16* __restrict__ xz,
                                               const float* __restrict__ cw,
                                               const float* __restrict__ cb,
                                               u16* __restrict__ ut) {
  __shared__ u16 sx[52][68];
  __shared__ u16 su2[49][68];
  const int d0 = blockIdx.x * 64;
  const int l0 = blockIdx.y * 49;
  const int b = blockIdx.z;
  const int t = threadIdx.x;
#pragma unroll
  for (int i = 0; i < 4; i++) {
    int idx = t + i * 256;
    if (idx < 832) {
      int row = idx >> 4, seg = idx & 15;
      int l = l0 - 3 + row;
      short4 v = {0, 0, 0, 0};
      if (l >= 0) {
        const u16* p = xz + (size_t)(b * LTOK + l) * (2 * D_INNER) + d0 + seg * 4;
        v = *(const short4*)p;
      }
      *(short4*)&sx[row][seg * 4] = v;
    }
  }
  __syncthreads();
  const int dl = t & 63, lg = t >> 6;
  const int d = d0 + dl;
  const float c0 = cw[d * 4], c1 = cw[d * 4 + 1], c2 = cw[d * 4 + 2],
              c3 = cw[d * 4 + 3];
  const float bb = cb[d];
  for (int l = lg; l < 49; l += 4) {
    float acc = bb;
    acc = fmaf(c0, bf2f(sx[l + 0][dl]), acc);
    acc = fmaf(c1, bf2f(sx[l + 1][dl]), acc);
    acc = fmaf(c2, bf2f(sx[l + 2][dl]), acc);
    acc = fmaf(c3, bf2f(sx[l + 3][dl]), acc);
    su2[l][dl] = f2bf(acc / (1.f + expf(-acc)));
  }
  __syncthreads();
#pragma unroll
  for (int i = 0; i < 13; i++) {
    int idx = t + i * 256;
    if (idx < 3136) {
      int d_ = idx / 49, l_ = idx % 49;
      ut[(size_t)(d0 + d_) * NROW + b * LTOK + l0 + l_] = su2[l_][d_];
    }
  }
}

// ---------- parallel selective scan: one block per (d, b); 16n x 14 chunks --
__global__ __launch_bounds__(256) void k_pscan(
    const float* __restrict__ dtt, const u16* __restrict__ ut,
    const u16* __restrict__ dblt, const float* __restrict__ A_log,
    const float* __restrict__ Dp, u16* __restrict__ yt) {
  __shared__ float sdA[16][199];
  __shared__ float sh[16][199];
  __shared__ float sC[16][199];
  __shared__ float sdt[196];
  __shared__ float su[196];
  __shared__ float ssA[16][16];
  __shared__ float ssB[16][16];
  const int d = blockIdx.x, b = blockIdx.y;
  const int t = threadIdx.x;
  const size_t col0 = (size_t)b * LTOK;
  if (t < 196) {
    sdt[t] = dtt[(size_t)d * NROW + col0 + t];
    su[t]  = bf2f(ut[(size_t)d * NROW + col0 + t]);
  }
  const int n = t & 15, c = t >> 4;   // c < 14 for t < 224
  float Breg[14];
  if (t < 224) {
    const u16* Bp = dblt + (size_t)(DT_RANK + n) * NROW + col0 + c * 14;
    const u16* Cp = dblt + (size_t)(DT_RANK + D_STATE + n) * NROW + col0 + c * 14;
#pragma unroll
    for (int j = 0; j < 14; j++) {
      Breg[j] = bf2f(Bp[j]);
      sC[n][c * 14 + j] = bf2f(Cp[j]);
    }
  }
  __syncthreads();
  if (t < 224) {
    const float a = -expf(A_log[(size_t)d * D_STATE + n]);
    float h = 0.f, p = 1.f;
#pragma unroll
    for (int j = 0; j < 14; j++) {
      int l = c * 14 + j;
      float dtv = sdt[l];
      float dA = expf(dtv * a);
      h = fmaf(dA, h, dtv * Breg[j] * su[l]);
      sdA[n][l] = dA;
      sh[n][l] = h;
      p *= dA;
    }
    ssA[n][c] = p;
    ssB[n][c] = h;
  }
  __syncthreads();
  // inclusive compose-scan over chunk dim (offsets 1,2,4,8)
  for (int off = 1; off < 14; off <<= 1) {
    float pA = 0.f, pB = 0.f;
    bool act = (t < 224) && (c >= off);
    if (act) { pA = ssA[n][c - off]; pB = ssB[n][c - off]; }
    __syncthreads();
    if (act) {
      float myA = ssA[n][c], myB = ssB[n][c];
      ssA[n][c] = myA * pA;
      ssB[n][c] = fmaf(myA, pB, myB);
    }
    __syncthreads();
  }
  if (t < 224) {
    float h0 = (c > 0) ? ssB[n][c - 1] : 0.f;
    if (h0 != 0.f) {
      float p = 1.f;
#pragma unroll
      for (int j = 0; j < 14; j++) {
        int l = c * 14 + j;
        p *= sdA[n][l];
        sh[n][l] = fmaf(p, h0, sh[n][l]);
      }
    }
  }
  __syncthreads();
  if (t < 196) {
    float y = 0.f;
#pragma unroll
    for (int nn = 0; nn < 16; nn++) y = fmaf(sh[nn][t], sC[nn][t], y);
    yt[(size_t)d * NROW + col0 + t] = f2bf(fmaf(Dp[d], su[t], y));
  }
}

// --------- transpose yt [d][r] -> yf [r][d], fused silu(z) gate -------------
__global__ __launch_bounds__(256) void k_trgate(const u16* __restrict__ yt,
                                                const u16* __restrict__ xz,
                                                u16* __restrict__ yf) {
  __shared__ u16 st[49][68];
  const int d0 = blockIdx.x * 64;
  const int l0 = blockIdx.y * 49;
  const int b = blockIdx.z;
  const int t = threadIdx.x;
#pragma unroll
  for (int i = 0; i < 13; i++) {
    int idx = t + i * 256;
    if (idx < 3136) {
      int d_ = idx / 49, l_ = idx % 49;
      st[l_][d_] = yt[(size_t)(d0 + d_) * NROW + b * LTOK + l0 + l_];
    }
  }
  __syncthreads();
#pragma unroll
  for (int i = 0; i < 13; i++) {
    int idx = t + i * 256;
    if (idx < 3136) {
      int l_ = idx >> 6, d_ = idx & 63;
      size_t r = (size_t)(b * LTOK + l0 + l_);
      float z = bf2f(xz[r * (2 * D_INNER) + D_INNER + d0 + d_]);  // silu'd
      yf[r * D_INNER + d0 + d_] = f2bf(bf2f(st[l_][d_]) * z);
    }
  }
}

// ---------------------- pool phase 1: partial sums over 14-token chunks -----
__global__ __launch_bounds__(128) void k_pool1(const float* __restrict__ tl,
                                               float* __restrict__ partial) {
  const int b = blockIdx.x, g = blockIdx.y, tid = threadIdx.x;
  float m[3] = {0.f, 0.f, 0.f};
  for (int l = g * 14; l < (g + 1) * 14; l++) {
    size_t row = ((size_t)b * LTOK + l) * D_MODEL;
#pragma unroll
    for (int j = 0; j < 3; j++) m[j] += tl[row + tid + j * 128];
  }
#pragma unroll
  for (int j = 0; j < 3; j++)
    partial[((size_t)b * 14 + g) * D_MODEL + tid + j * 128] = m[j];
}

// ------------------ pool phase 2: finalize mean + expmap0 -------------------
__global__ __launch_bounds__(128) void k_pool2(const float* __restrict__ partial,
                                               float* __restrict__ pooled,
                                               float* __restrict__ x2v) {
  __shared__ float sm[2];
  const int b = blockIdx.x, tid = threadIdx.x;
  float m[3] = {0.f, 0.f, 0.f};
  for (int g = 0; g < 14; g++) {
    size_t row = ((size_t)b * 14 + g) * D_MODEL;
#pragma unroll
    for (int j = 0; j < 3; j++) m[j] += partial[row + tid + j * 128];
  }
#pragma unroll
  for (int j = 0; j < 3; j++) m[j] *= (1.f / (float)LTOK);
  float s = blockSum128(m[0] * m[0] + m[1] * m[1] + m[2] * m[2], sm);
  float n = sqrtf(s + 1e-15f);
  float nc = clampf(n, 1e-8f, 5.f);
  float ke = tanhf(kSqrtC * nc) / (kSqrtC * nc);
  float rn = sqrtf(ke * ke * s + 1e-15f);
  float sc = rn > kMaxNorm ? kMaxNorm / rn : 1.f;
  float kk = ke * sc;
  float p[3];
#pragma unroll
  for (int j = 0; j < 3; j++) {
    p[j] = kk * m[j];
    pooled[(size_t)b * D_MODEL + tid + j * 128] = p[j];
  }
  float s2 = blockSum128(p[0] * p[0] + p[1] * p[1] + p[2] * p[2], sm);
  if (tid == 0) x2v[b] = s2;
}

// ------------------- hyperbolic distance head over prototypes ---------------
__global__ __launch_bounds__(256) void k_head(const float* __restrict__ pooled,
                                              const float* __restrict__ protos,
                                              const float* __restrict__ x2v,
                                              float* __restrict__ out) {
  __shared__ float sp[D_MODEL];
  const int b = blockIdx.y;
  const int c = blockIdx.x * 256 + threadIdx.x;
  for (int j = threadIdx.x; j < D_MODEL; j += 256)
    sp[j] = pooled[(size_t)b * D_MODEL + j];
  __syncthreads();
  if (c >= NCLS) return;
  const float* pr = protos + (size_t)c * D_MODEL;
  float dotv = 0.f, y2 = 0.f;
  for (int k = 0; k < D_MODEL; k++) {
    float w = pr[k];
    dotv += sp[k] * w;
    y2 += w * w;
  }
  float x2 = x2v[b];
  float xy = -dotv;
  float al = 1.f + xy + 0.5f * y2;
  float be = 1.f - 0.5f * x2;
  float num2 = al * al * x2 + 2.f * al * be * xy + be * be * y2;
  float den = fmaxf(1.f + xy + 0.25f * x2 * y2, 1e-15f);
  float r2 = num2 / (den * den) + 1e-15f;
  float dn = fminf(kSqrtC * sqrtf(r2), 1.f - 1e-5f);
  out[(size_t)b * NCLS + c] = -(2.f / kSqrtC) * atanhf(dn);
}

// ---------------------------------------------------------------------------
extern "C" void kernel_launch(void* const* d_in, const int* in_sizes, int n_in,
                              void* d_out, int out_size, void* d_ws,
                              size_t ws_size, hipStream_t stream) {
  const float* x        = (const float*)d_in[0];
  const float* patch_w  = (const float*)d_in[1];
  const float* patch_b  = (const float*)d_in[2];
  const float* hyp_w    = (const float*)d_in[3];
  const float* hyp_b    = (const float*)d_in[4];
  const float* pe_gamma = (const float*)d_in[5];
  const float* pe_beta  = (const float*)d_in[6];
  const float* pos      = (const float*)d_in[7];
  const float* in_w     = (const float*)d_in[8];
  const float* conv_w   = (const float*)d_in[9];
  const float* conv_b   = (const float*)d_in[10];
  const float* xp_w     = (const float*)d_in[11];
  const float* dt_w     = (const float*)d_in[12];
  const float* dt_bias  = (const float*)d_in[13];
  const float* A_log    = (const float*)d_in[14];
  const float* Dp       = (const float*)d_in[15];
  const float* out_w    = (const float*)d_in[16];
  const float* gamma    = (const float*)d_in[17];
  const float* beta     = (const float*)d_in[18];
  const float* gamma_f  = (const float*)d_in[19];
  const float* beta_f   = (const float*)d_in[20];
  const float* protos   = (const float*)d_in[21];
  float* out = (float*)d_out;

  // ---- workspace layout ----
  char* cur = (char*)d_ws;
  auto alloc = [&](size_t bytes) {
    char* p = cur;
    cur += (bytes + 255) & ~(size_t)255;
    return (void*)p;
  };
  float* hidden  = (float*)alloc((size_t)NROW * D_MODEL * 4);
  float* resid   = (float*)alloc((size_t)NROW * D_MODEL * 4);
  float* dtt     = (float*)alloc((size_t)D_INNER * NROW * 4);  // transposed dt
  float* xn      = (float*)alloc((size_t)NROW * 4);
  float* pooled  = (float*)alloc((size_t)BSZ * D_MODEL * 4);
  float* x2v     = (float*)alloc((size_t)BSZ * 4);
  float* partial = (float*)alloc((size_t)BSZ * 14 * D_MODEL * 4);
  u16* hn_bf  = (u16*)alloc((size_t)NROW * D_MODEL * 2);
  u16* xz_bf  = (u16*)alloc((size_t)NROW * 2 * D_INNER * 2);
  u16* dblt   = (u16*)alloc((size_t)64 * NROW * 2);            // transposed dbl
  u16* ut     = (u16*)alloc((size_t)D_INNER * NROW * 2);       // transposed u
  u16* yt     = (u16*)alloc((size_t)D_INNER * NROW * 2);       // transposed y
  u16* yf     = (u16*)alloc((size_t)NROW * D_INNER * 2);
  // bf16 weights
  const size_t n_inw  = (size_t)NDEPTH * 2 * D_INNER * D_MODEL;
  const size_t n_outw = (size_t)NDEPTH * D_MODEL * D_INNER;
  const size_t n_xpw  = (size_t)NDEPTH * NXP * D_INNER;
  const size_t n_dtw  = (size_t)NDEPTH * D_INNER * DT_RANK;
  const size_t n_pw   = (size_t)D_MODEL * 768;
  const size_t n_hw   = (size_t)D_MODEL * D_MODEL;
  u16* in_wb  = (u16*)alloc(n_inw * 2);
  u16* out_wb = (u16*)alloc(n_outw * 2);
  u16* xp_wb  = (u16*)alloc(n_xpw * 2);
  u16* dt_wb  = (u16*)alloc(n_dtw * 2);
  u16* p_wb   = (u16*)alloc(n_pw * 2);
  u16* h_wb   = (u16*)alloc(n_hw * 2);
  // stem/head aliases over dead regions
  u16* P_bf     = ut;                               // 3136x768 bf16 im2col
  float* tokens = dtt;                              // 3136x384 f32
  float* mx     = dtt + (size_t)NROW * D_MODEL;     // 3136x384 f32
  float* hnf    = dtt;                              // head: f32 logmap rows

  // ---- weight conversion (every call) ----
  k_cvt<<<dim3((int)((n_inw / 4 + 255) / 256)), dim3(256), 0, stream>>>(
      in_w, in_wb, (int)(n_inw / 4));
  k_cvt<<<dim3((int)((n_outw / 4 + 255) / 256)), dim3(256), 0, stream>>>(
      out_w, out_wb, (int)(n_outw / 4));
  k_cvt<<<dim3((int)((n_xpw / 4 + 255) / 256)), dim3(256), 0, stream>>>(
      xp_w, xp_wb, (int)(n_xpw / 4));
  k_cvt<<<dim3((int)((n_dtw / 4 + 255) / 256)), dim3(256), 0, stream>>>(
      dt_w, dt_wb, (int)(n_dtw / 4));
  k_cvt<<<dim3((int)((n_pw / 4 + 255) / 256)), dim3(256), 0, stream>>>(
      patch_w, p_wb, (int)(n_pw / 4));
  k_cvt<<<dim3((int)((n_hw / 4 + 255) / 256)), dim3(256), 0, stream>>>(
      hyp_w, h_wb, (int)(n_hw / 4));

  // ---- stem ----
  k_im2col<<<dim3((NROW * 768) / 256), dim3(256), 0, stream>>>(x, P_bf);
  k_gemm_bb<<<dim3(NROW / 64, 6), dim3(256), 0, stream>>>(
      P_bf, p_wb, patch_b, tokens, nullptr, 768, 768, D_MODEL, 0, D_MODEL, 0,
      0, 0);
  k_stem_a<<<dim3(NROW), dim3(128), 0, stream>>>(tokens, hn_bf, xn);
  k_gemm_bb<<<dim3(NROW / 64, 6), dim3(256), 0, stream>>>(
      hn_bf, h_wb, nullptr, mx, nullptr, D_MODEL, D_MODEL, D_MODEL, 0, D_MODEL,
      0, 0, 0);
  k_stem_b<<<dim3(NROW), dim3(128), 0, stream>>>(mx, xn, hyp_b, pe_gamma,
                                                 pe_beta, pos, hidden);
  // ---- layers ----
  for (int i = 0; i < NDEPTH; i++) {
    k_resln<<<dim3(NROW / 4), dim3(256), 0, stream>>>(
        hidden, resid, resid, gamma + (size_t)i * D_MODEL,
        beta + (size_t)i * D_MODEL, hn_bf, nullptr, i == 0 ? 1 : 0, 0);
    // in_proj (z-half gets SiLU fused), bf16 out [r, 1536]
    k_gemm_bb<<<dim3(NROW / 64, 24), dim3(256), 0, stream>>>(
        hn_bf, in_wb + (size_t)i * 2 * D_INNER * D_MODEL, nullptr, xz_bf,
        nullptr, D_MODEL, D_MODEL, 2 * D_INNER, 0, 2 * D_INNER, 2, 1, 0);
    // conv + silu -> ut (transposed)
    k_convt<<<dim3(12, 4, BSZ), dim3(256), 0, stream>>>(
        xz_bf, conv_w + (size_t)i * D_INNER * 4, conv_b + (size_t)i * D_INNER,
        ut);
    // x_proj: A = ut (transposed read), out = dblt (transposed bf16)
    k_gemm_bb<<<dim3(NROW / 64, 1), dim3(256), 0, stream>>>(
        ut, xp_wb + (size_t)i * NXP * D_INNER, nullptr, nullptr, dblt, D_INNER,
        NROW, 0, NROW, NXP, 0, 1, 1);
    // dt_proj: A = dblt rows 0..23 (transposed read), softplus, out dtt f32^T
    k_gemm_bb<<<dim3(NROW / 64, 12), dim3(256), 0, stream>>>(
        dblt, dt_wb + (size_t)i * D_INNER * DT_RANK,
        dt_bias + (size_t)i * D_INNER, nullptr, dtt, DT_RANK, NROW, 0, NROW,
        D_INNER, 1, 0, 1);
    // parallel scan -> yt = y + D*u (transposed)
    k_pscan<<<dim3(D_INNER, BSZ), dim3(256), 0, stream>>>(
        dtt, ut, dblt, A_log + (size_t)i * D_INNER * D_STATE,
        Dp + (size_t)i * D_INNER, yt);
    // transpose + silu(z) gate -> yf [r, 768]
    k_trgate<<<dim3(12, 4, BSZ), dim3(256), 0, stream>>>(yt, xz_bf, yf);
    k_gemm_bb<<<dim3(NROW / 64, 6), dim3(256), 0, stream>>>(
        yf, out_wb + (size_t)i * D_MODEL * D_INNER, nullptr, hidden, nullptr,
        D_INNER, D_INNER, D_MODEL, 0, D_MODEL, 0, 0, 0);
  }
  // ---- head ----
  k_resln<<<dim3(NROW / 4), dim3(256), 0, stream>>>(
      hidden, resid, resid, gamma_f, beta_f, nullptr, hnf, 0, 1);
  k_pool1<<<dim3(BSZ, 14), dim3(128), 0, stream>>>(hnf, partial);
  k_pool2<<<dim3(BSZ), dim3(128), 0, stream>>>(partial, pooled, x2v);
  k_head<<<dim3((NCLS + 255) / 256, BSZ), dim3(256), 0, stream>>>(pooled,
                                                                  protos, x2v,
                                                                  out);
}

// Round 6
// 3399.383 us; speedup vs baseline: 1.5858x; 1.5858x over previous
//
#include <hip/hip_runtime.h>
#include <hip/hip_bf16.h>
#include <math.h>

#define D_MODEL 384
#define D_INNER 768
#define D_STATE 16
#define DT_RANK 24
#define NXP 56          // DT_RANK + 2*D_STATE
#define LTOK 196
#define BSZ 16
#define NROW 3136       // BSZ * LTOK
#define NDEPTH 24
#define NCLS 1000

constexpr float kSqrtC   = 0.70710678118654752440f;
constexpr float kMaxNorm = 0.95f / 0.70710678118654752440f;   // 1.3435029...

typedef unsigned short u16;
typedef short  bf16x8 __attribute__((ext_vector_type(8)));
typedef u16    u16x8  __attribute__((ext_vector_type(8)));
typedef float  f32x4  __attribute__((ext_vector_type(4)));

__device__ __forceinline__ float clampf(float x, float lo, float hi) {
  return fminf(fmaxf(x, lo), hi);
}

// f32 -> bf16 (RNE)
__device__ __forceinline__ u16 f2bf(float f) {
  union { float f; unsigned u; } v; v.f = f;
  return (u16)((v.u + 0x7FFFu + ((v.u >> 16) & 1u)) >> 16);
}
// bf16 -> f32
__device__ __forceinline__ float bf2f(u16 s) {
  union { unsigned u; float f; } v; v.u = ((unsigned)s) << 16;
  return v.f;
}

// 64-lane wave reduction (no LDS, no barriers)
__device__ __forceinline__ float waveSum(float v) {
#pragma unroll
  for (int o = 1; o < 64; o <<= 1) v += __shfl_xor(v, o, 64);
  return v;
}

// block=128 sum-reduce with broadcast (stem kernels only).
__device__ __forceinline__ float blockSum128(float v, float* sm) {
#pragma unroll
  for (int o = 32; o > 0; o >>= 1) v += __shfl_down(v, o, 64);
  __syncthreads();
  if ((threadIdx.x & 63) == 0) sm[threadIdx.x >> 6] = v;
  __syncthreads();
  return sm[0] + sm[1];
}

// --------------------------- f32 -> bf16 bulk convert (weights, per call) ---
__global__ __launch_bounds__(256) void k_cvt(const float* __restrict__ s,
                                             u16* __restrict__ d, int n4) {
  int i = blockIdx.x * 256 + threadIdx.x;
  if (i >= n4) return;
  float4 v = ((const float4*)s)[i];
  short4 o = {(short)f2bf(v.x), (short)f2bf(v.y), (short)f2bf(v.z),
              (short)f2bf(v.w)};
  *(short4*)&d[(size_t)i * 4] = o;
}

// ------------------------------------------------- im2col (emit bf16) ------
__global__ __launch_bounds__(256) void k_im2col(const float* __restrict__ x,
                                                u16* __restrict__ P) {
  size_t idx = (size_t)blockIdx.x * 256 + threadIdx.x;
  if (idx >= (size_t)NROW * 768) return;
  int k = (int)(idx % 768);
  int r = (int)(idx / 768);
  int b = r / LTOK, t = r % LTOK;
  int hp = t / 14, wp = t % 14;
  int c = k / 256, rem = k % 256, i = rem / 16, j = rem % 16;
  P[idx] = f2bf(
      x[(((size_t)(b * 3 + c) * 224) + hp * 16 + i) * 224 + wp * 16 + j]);
}

// ------------------------- pure-bf16 MFMA GEMM: C = A * W^T (+bias, act) ----
// A (M,K) bf16 rm stride lda. W (Nv,K) bf16 rm tight. Outputs: Cn (normal
// [r][cg], stride ldc) and/or Ct (transposed [cg][r], stride ldct); null to
// skip. obf: bf16 outputs, else f32. act: 0 none, 1 softplus(+bias),
// 2 silu if cg>=768.
#define LDA 40
__global__ __launch_bounds__(256) void k_gemm_bb(
    const u16* __restrict__ A, const u16* __restrict__ W,
    const float* __restrict__ bias, void* __restrict__ Cn,
    void* __restrict__ Ct, int K, int lda, int ldc, int ldct, int Nv, int act,
    int obf) {
  __shared__ u16 As[64 * LDA];
  __shared__ u16 Ws[64 * LDA];
  const int tid = threadIdx.x;
  const int m0 = blockIdx.x * 64;
  const int n0 = blockIdx.y * 64;
  const int lane = tid & 63;
  const int wave = tid >> 6;
  const int wm = wave & 1, wn = wave >> 1;
  const int lm = lane & 15;
  const int quad = lane >> 4;
  const int srow = tid >> 2;
  const int sseg = tid & 3;

  f32x4 acc[2][2];
#pragma unroll
  for (int i = 0; i < 2; i++)
#pragma unroll
    for (int j = 0; j < 2; j++) acc[i][j] = (f32x4){0.f, 0.f, 0.f, 0.f};

  const u16* rowA = A + (size_t)(m0 + srow) * lda + sseg * 8;
  const int wrow = n0 + srow;
  const u16* rowW = W + (size_t)wrow * K + sseg * 8;
  const bool wvalid = wrow < Nv;

  for (int k0 = 0; k0 < K; k0 += 32) {
    u16x8 av = {0, 0, 0, 0, 0, 0, 0, 0}, wv = {0, 0, 0, 0, 0, 0, 0, 0};
    if (k0 + 32 <= K) {
      av = *(const u16x8*)(rowA + k0);
      if (wvalid) wv = *(const u16x8*)(rowW + k0);
    } else {
#pragma unroll
      for (int kk = 0; kk < 8; kk++) {
        int k = k0 + sseg * 8 + kk;
        if (k < K) {
          av[kk] = rowA[k0 + kk];
          if (wvalid) wv[kk] = rowW[k0 + kk];
        }
      }
    }
    __syncthreads();  // guard LDS reuse from previous iter's reads
    *(u16x8*)&As[srow * LDA + sseg * 8] = av;
    *(u16x8*)&Ws[srow * LDA + sseg * 8] = wv;
    __syncthreads();
    bf16x8 af[2], bfr[2];
#pragma unroll
    for (int i = 0; i < 2; i++) {
      af[i]  = *(bf16x8*)&As[(wm * 32 + i * 16 + lm) * LDA + quad * 8];
      bfr[i] = *(bf16x8*)&Ws[(wn * 32 + i * 16 + lm) * LDA + quad * 8];
    }
#pragma unroll
    for (int i = 0; i < 2; i++)
#pragma unroll
      for (int j = 0; j < 2; j++)
        acc[i][j] = __builtin_amdgcn_mfma_f32_16x16x32_bf16(af[i], bfr[j],
                                                            acc[i][j], 0, 0, 0);
  }
  // epilogue: C/D layout col=lane&15, row=quad*4+reg
#pragma unroll
  for (int i = 0; i < 2; i++) {
#pragma unroll
    for (int j = 0; j < 2; j++) {
      int cg = n0 + wn * 32 + j * 16 + lm;
      if (cg >= Nv) continue;
      float bj = bias ? bias[cg] : 0.f;
      float o[4];
      int rgb = m0 + wm * 32 + i * 16 + quad * 4;
#pragma unroll
      for (int reg = 0; reg < 4; reg++) {
        float v = acc[i][j][reg] + bj;
        if (act == 1) v = (v > 20.f) ? v : log1pf(expf(v));
        else if (act == 2 && cg >= 768) v = v / (1.f + expf(-v));
        o[reg] = v;
      }
      if (Cn) {
#pragma unroll
        for (int reg = 0; reg < 4; reg++) {
          if (obf) ((u16*)Cn)[(size_t)(rgb + reg) * ldc + cg] = f2bf(o[reg]);
          else ((float*)Cn)[(size_t)(rgb + reg) * ldc + cg] = o[reg];
        }
      }
      if (Ct) {
        if (obf) {
          short4 o4 = {(short)f2bf(o[0]), (short)f2bf(o[1]), (short)f2bf(o[2]),
                       (short)f2bf(o[3])};
          *(short4*)&((u16*)Ct)[(size_t)cg * ldct + rgb] = o4;
        } else {
          float4 o4 = {o[0], o[1], o[2], o[3]};
          *(float4*)&((float*)Ct)[(size_t)cg * ldct + rgb] = o4;
        }
      }
    }
  }
}

// ------------------ stem a: expmap0(tokens) -> bf16 h + ||h|| ---------------
__global__ __launch_bounds__(128) void k_stem_a(const float* __restrict__ tok,
                                                u16* __restrict__ hb,
                                                float* __restrict__ xn) {
  __shared__ float sm[2];
  const int r = blockIdx.x, tid = threadIdx.x;
  float v[3];
#pragma unroll
  for (int j = 0; j < 3; j++) v[j] = tok[(size_t)r * D_MODEL + tid + j * 128];
  float s = blockSum128(v[0] * v[0] + v[1] * v[1] + v[2] * v[2], sm);
  float n = sqrtf(s + 1e-15f);
  float nc = clampf(n, 1e-8f, 5.f);
  float ke = tanhf(kSqrtC * nc) / (kSqrtC * nc);
  float rn = sqrtf(ke * ke * s + 1e-15f);
  float sc = rn > kMaxNorm ? kMaxNorm / rn : 1.f;
  float kk = ke * sc;
#pragma unroll
  for (int j = 0; j < 3; j++)
    hb[(size_t)r * D_MODEL + tid + j * 128] = f2bf(kk * v[j]);
  if (tid == 0) xn[r] = fmaxf(sqrtf(kk * kk * s + 1e-15f), 1e-8f);
}

// --- stem b: mobius_matvec tail + mobius_add(hyp_b) + hyp_LN + pos + expmap -
__global__ __launch_bounds__(128) void k_stem_b(
    const float* __restrict__ mx, const float* __restrict__ xn,
    const float* __restrict__ hyp_b, const float* __restrict__ pe_g,
    const float* __restrict__ pe_b, const float* __restrict__ pos,
    float* __restrict__ outh) {
  __shared__ float sm[2];
  const int r = blockIdx.x, tid = threadIdx.x;
  const int t = r % LTOK;
  float mv[3], bv[3];
  int dd[3];
#pragma unroll
  for (int j = 0; j < 3; j++) {
    dd[j] = tid + j * 128;
    mv[j] = mx[(size_t)r * D_MODEL + dd[j]];
    bv[j] = hyp_b[dd[j]];
  }
  float smx = blockSum128(mv[0] * mv[0] + mv[1] * mv[1] + mv[2] * mv[2], sm);
  float mxn = fmaxf(sqrtf(smx + 1e-15f), 1e-8f);
  float xnv = xn[r];
  float tt = tanhf(mxn / xnv * atanhf(fminf(kSqrtC * xnv, 1.f - 1e-5f)));
  float kres = tt / (mxn * kSqrtC);
  float res[3];
#pragma unroll
  for (int j = 0; j < 3; j++) res[j] = kres * mv[j];
  float xy = blockSum128(res[0] * bv[0] + res[1] * bv[1] + res[2] * bv[2], sm);
  float y2 = blockSum128(bv[0] * bv[0] + bv[1] * bv[1] + bv[2] * bv[2], sm);
  float x2 = kres * kres * smx;
  float al = 1.f + xy + 0.5f * y2;
  float be = 1.f - 0.5f * x2;
  float den = fmaxf(1.f + xy + 0.25f * x2 * y2, 1e-15f);
  float h1[3];
#pragma unroll
  for (int j = 0; j < 3; j++) h1[j] = (al * res[j] + be * bv[j]) / den;
  float s1 = blockSum128(h1[0] * h1[0] + h1[1] * h1[1] + h1[2] * h1[2], sm);
  float n1 = sqrtf(s1 + 1e-15f);
  float nc1 = clampf(n1, 1e-8f, kMaxNorm);
  float kl = atanhf(fminf(kSqrtC * nc1, 0.95f)) / (kSqrtC * nc1);
  float tl[3];
#pragma unroll
  for (int j = 0; j < 3; j++) tl[j] = kl * h1[j];
  float mean = blockSum128(tl[0] + tl[1] + tl[2], sm) * (1.f / 384.f);
  float dv = 0.f;
#pragma unroll
  for (int j = 0; j < 3; j++) { float d = tl[j] - mean; dv += d * d; }
  float var = blockSum128(dv, sm) * (1.f / 383.f);
  float inv = 1.f / (sqrtf(var) + 1e-5f);
  float g[3];
#pragma unroll
  for (int j = 0; j < 3; j++)
    g[j] = (tl[j] - mean) * inv * pe_g[dd[j]] + pe_b[dd[j]];
  float sg = blockSum128(g[0] * g[0] + g[1] * g[1] + g[2] * g[2], sm);
  float ng = sqrtf(sg + 1e-15f);
  float nc2 = clampf(ng, 1e-8f, 5.f);
  float ke = tanhf(kSqrtC * nc2) / (kSqrtC * nc2);
  float rn = sqrtf(ke * ke * sg + 1e-15f);
  float sc = rn > kMaxNorm ? kMaxNorm / rn : 1.f;
  float kk = ke * sc;
  float s2 = kk * kk * sg;
  float n3 = sqrtf(s2 + 1e-15f);
  float nc3 = clampf(n3, 1e-8f, kMaxNorm);
  float kl2 = atanhf(fminf(kSqrtC * nc3, 0.95f)) / (kSqrtC * nc3);
  float v[3];
#pragma unroll
  for (int j = 0; j < 3; j++)
    v[j] = kl2 * kk * g[j] + pos[(size_t)t * D_MODEL + dd[j]];
  float sv = blockSum128(v[0] * v[0] + v[1] * v[1] + v[2] * v[2], sm);
  float nv = sqrtf(sv + 1e-15f);
  float nc4 = clampf(nv, 1e-8f, 5.f);
  float ke2 = tanhf(kSqrtC * nc4) / (kSqrtC * nc4);
  float rn2 = sqrtf(ke2 * ke2 * sv + 1e-15f);
  float sc2 = rn2 > kMaxNorm ? kMaxNorm / rn2 : 1.f;
#pragma unroll
  for (int j = 0; j < 3; j++)
    outh[(size_t)r * D_MODEL + dd[j]] = ke2 * sc2 * v[j];
}

// --- residual accumulate + hyp_layernorm, one wave per row (no barriers) ----
__global__ __launch_bounds__(256) void k_resln(
    const float* __restrict__ hid, const float* __restrict__ res_in,
    float* __restrict__ res_out, const float* __restrict__ g_,
    const float* __restrict__ b_, u16* __restrict__ out_bf,
    float* __restrict__ out_f, int first, int out_logmap) {
  const int lane = threadIdx.x & 63;
  const int r = blockIdx.x * 4 + (threadIdx.x >> 6);
  float v[6];
  int dd[6];
#pragma unroll
  for (int j = 0; j < 6; j++) {
    dd[j] = lane + j * 64;
    size_t idx = (size_t)r * D_MODEL + dd[j];
    v[j] = hid[idx] + (first ? 0.f : res_in[idx]);
    res_out[idx] = v[j];
  }
  float ss = 0.f;
#pragma unroll
  for (int j = 0; j < 6; j++) ss += v[j] * v[j];
  float s = waveSum(ss);
  float n = sqrtf(s + 1e-15f);
  float nc = clampf(n, 1e-8f, kMaxNorm);
  float kl = atanhf(fminf(kSqrtC * nc, 0.95f)) / (kSqrtC * nc);
  float t[6];
  float ts = 0.f;
#pragma unroll
  for (int j = 0; j < 6; j++) { t[j] = kl * v[j]; ts += t[j]; }
  float mean = waveSum(ts) * (1.f / 384.f);
  float dv = 0.f;
#pragma unroll
  for (int j = 0; j < 6; j++) { float d = t[j] - mean; dv += d * d; }
  float var = waveSum(dv) * (1.f / 383.f);
  float inv = 1.f / (sqrtf(var) + 1e-5f);
  float g[6];
  float gs = 0.f;
#pragma unroll
  for (int j = 0; j < 6; j++) {
    g[j] = (t[j] - mean) * inv * g_[dd[j]] + b_[dd[j]];
    gs += g[j] * g[j];
  }
  float sg = waveSum(gs);
  float ng = sqrtf(sg + 1e-15f);
  float nc2 = clampf(ng, 1e-8f, 5.f);
  float ke = tanhf(kSqrtC * nc2) / (kSqrtC * nc2);
  float rn = sqrtf(ke * ke * sg + 1e-15f);
  float sc = rn > kMaxNorm ? kMaxNorm / rn : 1.f;
  float kk = ke * sc;
  if (!out_logmap) {
#pragma unroll
    for (int j = 0; j < 6; j++)
      out_bf[(size_t)r * D_MODEL + dd[j]] = f2bf(kk * g[j]);
  } else {
    float s2 = kk * kk * sg;
    float n3 = sqrtf(s2 + 1e-15f);
    float nc3 = clampf(n3, 1e-8f, kMaxNorm);
    float kl2 = atanhf(fminf(kSqrtC * nc3, 0.95f)) / (kSqrtC * nc3);
#pragma unroll
    for (int j = 0; j < 6; j++)
      out_f[(size_t)r * D_MODEL + dd[j]] = kl2 * kk * g[j];
  }
}

// -- conv1d(k=4, causal) + SiLU, tiled; writes u transposed AND normal -------
__global__ __launch_bounds__(256) void k_convt(const u16* __restrict__ xz,
                                               const float* __restrict__ cw,
                                               const float* __restrict__ cb,
                                               u16* __restrict__ ut,
                                               u16* __restrict__ un) {
  __shared__ u16 sx[52][68];
  __shared__ u16 su2[49][68];
  const int d0 = blockIdx.x * 64;
  const int l0 = blockIdx.y * 49;
  const int b = blockIdx.z;
  const int t = threadIdx.x;
#pragma unroll
  for (int i = 0; i < 4; i++) {
    int idx = t + i * 256;
    if (idx < 832) {
      int row = idx >> 4, seg = idx & 15;
      int l = l0 - 3 + row;
      short4 v = {0, 0, 0, 0};
      if (l >= 0) {
        const u16* p = xz + (size_t)(b * LTOK + l) * (2 * D_INNER) + d0 + seg * 4;
        v = *(const short4*)p;
      }
      *(short4*)&sx[row][seg * 4] = v;
    }
  }
  __syncthreads();
  const int dl = t & 63, lg = t >> 6;
  const int d = d0 + dl;
  const float c0 = cw[d * 4], c1 = cw[d * 4 + 1], c2 = cw[d * 4 + 2],
              c3 = cw[d * 4 + 3];
  const float bb = cb[d];
  for (int l = lg; l < 49; l += 4) {
    float acc = bb;
    acc = fmaf(c0, bf2f(sx[l + 0][dl]), acc);
    acc = fmaf(c1, bf2f(sx[l + 1][dl]), acc);
    acc = fmaf(c2, bf2f(sx[l + 2][dl]), acc);
    acc = fmaf(c3, bf2f(sx[l + 3][dl]), acc);
    su2[l][dl] = f2bf(acc / (1.f + expf(-acc)));
  }
  __syncthreads();
#pragma unroll
  for (int i = 0; i < 13; i++) {
    int idx = t + i * 256;
    if (idx < 3136) {
      int d_ = idx / 49, l_ = idx % 49;
      ut[(size_t)(d0 + d_) * NROW + b * LTOK + l0 + l_] = su2[l_][d_];
    }
  }
#pragma unroll
  for (int i = 0; i < 13; i++) {
    int idx = t + i * 256;
    if (idx < 3136) {
      int l_ = idx >> 6, d_ = idx & 63;
      un[(size_t)(b * LTOK + l0 + l_) * D_INNER + d0 + d_] = su2[l_][d_];
    }
  }
}

// ---------- parallel selective scan v2: registers for chunk state -----------
// One block per (d, b). Thread (n = t&15, c = t>>4), c<14 active: 14-token
// chunk scan in registers, 14x17-padded LDS only for chunk summaries.
__global__ __launch_bounds__(256) void k_pscan(
    const float* __restrict__ dtt, const u16* __restrict__ ut,
    const u16* __restrict__ dblt, const float* __restrict__ A_log,
    const float* __restrict__ Dp, u16* __restrict__ yt) {
  __shared__ float sdt[196];
  __shared__ float su[196];
  __shared__ float ssA[14][17];
  __shared__ float ssB[14][17];
  const int d = blockIdx.x, b = blockIdx.y;
  const int t = threadIdx.x;
  const size_t col0 = (size_t)b * LTOK;
  if (t < 196) {
    sdt[t] = dtt[(size_t)d * NROW + col0 + t];
    su[t]  = bf2f(ut[(size_t)d * NROW + col0 + t]);
  }
  const int n = t & 15, c = t >> 4;
  const bool act = t < 224;
  float Breg[14], Creg[14], dA[14], hh[14];
  float a = 0.f;
  if (act) {
    a = -expf(A_log[(size_t)d * D_STATE + n]);
    const u16* Bp = dblt + (size_t)(DT_RANK + n) * NROW + col0 + c * 14;
    const u16* Cp =
        dblt + (size_t)(DT_RANK + D_STATE + n) * NROW + col0 + c * 14;
#pragma unroll
    for (int j = 0; j < 14; j++) {
      Breg[j] = bf2f(Bp[j]);
      Creg[j] = bf2f(Cp[j]);
    }
  }
  __syncthreads();
  if (act) {
    float h = 0.f, p = 1.f;
#pragma unroll
    for (int j = 0; j < 14; j++) {
      int l = c * 14 + j;
      float dtv = sdt[l];
      float e = expf(dtv * a);
      h = fmaf(e, h, dtv * Breg[j] * su[l]);
      dA[j] = e;
      hh[j] = h;
      p *= e;
    }
    ssA[c][n] = p;
    ssB[c][n] = h;
  }
  __syncthreads();
  // inclusive compose-scan over chunk dim (offsets 1,2,4,8)
  for (int off = 1; off < 14; off <<= 1) {
    float pA = 0.f, pB = 0.f;
    bool w = act && (c >= off);
    if (w) { pA = ssA[c - off][n]; pB = ssB[c - off][n]; }
    __syncthreads();
    if (w) {
      float myA = ssA[c][n], myB = ssB[c][n];
      ssA[c][n] = myA * pA;
      ssB[c][n] = fmaf(myA, pB, myB);
    }
    __syncthreads();
  }
  if (act) {
    float h0 = (c > 0) ? ssB[c - 1][n] : 0.f;
    float yl[14];
    float p = 1.f;
#pragma unroll
    for (int j = 0; j < 14; j++) {
      p *= dA[j];
      float hv = fmaf(p, h0, hh[j]);
      yl[j] = hv * Creg[j];
    }
    // reduce across the 16 n-lanes (contiguous lanes within the wave)
#pragma unroll
    for (int j = 0; j < 14; j++) {
      float y = yl[j];
      y += __shfl_xor(y, 1, 64);
      y += __shfl_xor(y, 2, 64);
      y += __shfl_xor(y, 4, 64);
      y += __shfl_xor(y, 8, 64);
      yl[j] = y;
    }
    if (n == 0) {
      const float Dv = Dp[d];
#pragma unroll
      for (int j = 0; j < 14; j++) {
        int l = c * 14 + j;
        yt[(size_t)d * NROW + col0 + l] = f2bf(fmaf(Dv, su[l], yl[j]));
      }
    }
  }
}

// --------- transpose yt [d][r] -> yf [r][d], fused silu(z) gate -------------
__global__ __launch_bounds__(256) void k_trgate(const u16* __restrict__ yt,
                                                const u16* __restrict__ xz,
                                                u16* __restrict__ yf) {
  __shared__ u16 st[49][68];
  const int d0 = blockIdx.x * 64;
  const int l0 = blockIdx.y * 49;
  const int b = blockIdx.z;
  const int t = threadIdx.x;
#pragma unroll
  for (int i = 0; i < 13; i++) {
    int idx = t + i * 256;
    if (idx < 3136) {
      int d_ = idx / 49, l_ = idx % 49;
      st[l_][d_] = yt[(size_t)(d0 + d_) * NROW + b * LTOK + l0 + l_];
    }
  }
  __syncthreads();
#pragma unroll
  for (int i = 0; i < 13; i++) {
    int idx = t + i * 256;
    if (idx < 3136) {
      int l_ = idx >> 6, d_ = idx & 63;
      size_t r = (size_t)(b * LTOK + l0 + l_);
      float z = bf2f(xz[r * (2 * D_INNER) + D_INNER + d0 + d_]);  // silu'd
      yf[r * D_INNER + d0 + d_] = f2bf(bf2f(st[l_][d_]) * z);
    }
  }
}

// ---------------------- pool phase 1: partial sums over 14-token chunks -----
__global__ __launch_bounds__(128) void k_pool1(const float* __restrict__ tl,
                                               float* __restrict__ partial) {
  const int b = blockIdx.x, g = blockIdx.y, tid = threadIdx.x;
  float m[3] = {0.f, 0.f, 0.f};
  for (int l = g * 14; l < (g + 1) * 14; l++) {
    size_t row = ((size_t)b * LTOK + l) * D_MODEL;
#pragma unroll
    for (int j = 0; j < 3; j++) m[j] += tl[row + tid + j * 128];
  }
#pragma unroll
  for (int j = 0; j < 3; j++)
    partial[((size_t)b * 14 + g) * D_MODEL + tid + j * 128] = m[j];
}

// ------------------ pool phase 2: finalize mean + expmap0 -------------------
__global__ __launch_bounds__(128) void k_pool2(const float* __restrict__ partial,
                                               float* __restrict__ pooled,
                                               float* __restrict__ x2v) {
  __shared__ float sm[2];
  const int b = blockIdx.x, tid = threadIdx.x;
  float m[3] = {0.f, 0.f, 0.f};
  for (int g = 0; g < 14; g++) {
    size_t row = ((size_t)b * 14 + g) * D_MODEL;
#pragma unroll
    for (int j = 0; j < 3; j++) m[j] += partial[row + tid + j * 128];
  }
#pragma unroll
  for (int j = 0; j < 3; j++) m[j] *= (1.f / (float)LTOK);
  float s = blockSum128(m[0] * m[0] + m[1] * m[1] + m[2] * m[2], sm);
  float n = sqrtf(s + 1e-15f);
  float nc = clampf(n, 1e-8f, 5.f);
  float ke = tanhf(kSqrtC * nc) / (kSqrtC * nc);
  float rn = sqrtf(ke * ke * s + 1e-15f);
  float sc = rn > kMaxNorm ? kMaxNorm / rn : 1.f;
  float kk = ke * sc;
  float p[3];
#pragma unroll
  for (int j = 0; j < 3; j++) {
    p[j] = kk * m[j];
    pooled[(size_t)b * D_MODEL + tid + j * 128] = p[j];
  }
  float s2 = blockSum128(p[0] * p[0] + p[1] * p[1] + p[2] * p[2], sm);
  if (tid == 0) x2v[b] = s2;
}

// ------------------- hyperbolic distance head over prototypes ---------------
__global__ __launch_bounds__(256) void k_head(const float* __restrict__ pooled,
                                              const float* __restrict__ protos,
                                              const float* __restrict__ x2v,
                                              float* __restrict__ out) {
  __shared__ float sp[D_MODEL];
  const int b = blockIdx.y;
  const int c = blockIdx.x * 256 + threadIdx.x;
  for (int j = threadIdx.x; j < D_MODEL; j += 256)
    sp[j] = pooled[(size_t)b * D_MODEL + j];
  __syncthreads();
  if (c >= NCLS) return;
  const float* pr = protos + (size_t)c * D_MODEL;
  float dotv = 0.f, y2 = 0.f;
  for (int k = 0; k < D_MODEL; k++) {
    float w = pr[k];
    dotv += sp[k] * w;
    y2 += w * w;
  }
  float x2 = x2v[b];
  float xy = -dotv;
  float al = 1.f + xy + 0.5f * y2;
  float be = 1.f - 0.5f * x2;
  float num2 = al * al * x2 + 2.f * al * be * xy + be * be * y2;
  float den = fmaxf(1.f + xy + 0.25f * x2 * y2, 1e-15f);
  float r2 = num2 / (den * den) + 1e-15f;
  float dn = fminf(kSqrtC * sqrtf(r2), 1.f - 1e-5f);
  out[(size_t)b * NCLS + c] = -(2.f / kSqrtC) * atanhf(dn);
}

// ---------------------------------------------------------------------------
extern "C" void kernel_launch(void* const* d_in, const int* in_sizes, int n_in,
                              void* d_out, int out_size, void* d_ws,
                              size_t ws_size, hipStream_t stream) {
  const float* x        = (const float*)d_in[0];
  const float* patch_w  = (const float*)d_in[1];
  const float* patch_b  = (const float*)d_in[2];
  const float* hyp_w    = (const float*)d_in[3];
  const float* hyp_b    = (const float*)d_in[4];
  const float* pe_gamma = (const float*)d_in[5];
  const float* pe_beta  = (const float*)d_in[6];
  const float* pos      = (const float*)d_in[7];
  const float* in_w     = (const float*)d_in[8];
  const float* conv_w   = (const float*)d_in[9];
  const float* conv_b   = (const float*)d_in[10];
  const float* xp_w     = (const float*)d_in[11];
  const float* dt_w     = (const float*)d_in[12];
  const float* dt_bias  = (const float*)d_in[13];
  const float* A_log    = (const float*)d_in[14];
  const float* Dp       = (const float*)d_in[15];
  const float* out_w    = (const float*)d_in[16];
  const float* gamma    = (const float*)d_in[17];
  const float* beta     = (const float*)d_in[18];
  const float* gamma_f  = (const float*)d_in[19];
  const float* beta_f   = (const float*)d_in[20];
  const float* protos   = (const float*)d_in[21];
  float* out = (float*)d_out;

  // ---- workspace layout ----
  char* cur = (char*)d_ws;
  auto alloc = [&](size_t bytes) {
    char* p = cur;
    cur += (bytes + 255) & ~(size_t)255;
    return (void*)p;
  };
  float* hidden  = (float*)alloc((size_t)NROW * D_MODEL * 4);
  float* resid   = (float*)alloc((size_t)NROW * D_MODEL * 4);
  float* dtt     = (float*)alloc((size_t)D_INNER * NROW * 4);  // dt^T f32
  float* xn      = (float*)alloc((size_t)NROW * 4);
  float* pooled  = (float*)alloc((size_t)BSZ * D_MODEL * 4);
  float* x2v     = (float*)alloc((size_t)BSZ * 4);
  float* partial = (float*)alloc((size_t)BSZ * 14 * D_MODEL * 4);
  u16* hn_bf  = (u16*)alloc((size_t)NROW * D_MODEL * 2);
  u16* xz_bf  = (u16*)alloc((size_t)NROW * 2 * D_INNER * 2);
  u16* dblt   = (u16*)alloc((size_t)64 * NROW * 2);            // dbl^T bf16
  u16* dbl_n  = (u16*)alloc((size_t)NROW * NXP * 2);           // dbl normal
  u16* ut     = (u16*)alloc((size_t)D_INNER * NROW * 2);       // u^T
  u16* u_bf   = (u16*)alloc((size_t)NROW * D_INNER * 2);       // u normal
  u16* yt     = (u16*)alloc((size_t)D_INNER * NROW * 2);       // y^T
  u16* yf     = (u16*)alloc((size_t)NROW * D_INNER * 2);
  // bf16 weights
  const size_t n_inw  = (size_t)NDEPTH * 2 * D_INNER * D_MODEL;
  const size_t n_outw = (size_t)NDEPTH * D_MODEL * D_INNER;
  const size_t n_xpw  = (size_t)NDEPTH * NXP * D_INNER;
  const size_t n_dtw  = (size_t)NDEPTH * D_INNER * DT_RANK;
  const size_t n_pw   = (size_t)D_MODEL * 768;
  const size_t n_hw   = (size_t)D_MODEL * D_MODEL;
  u16* in_wb  = (u16*)alloc(n_inw * 2);
  u16* out_wb = (u16*)alloc(n_outw * 2);
  u16* xp_wb  = (u16*)alloc(n_xpw * 2);
  u16* dt_wb  = (u16*)alloc(n_dtw * 2);
  u16* p_wb   = (u16*)alloc(n_pw * 2);
  u16* h_wb   = (u16*)alloc(n_hw * 2);
  // stem/head aliases over dead regions
  u16* P_bf     = ut;                               // 3136x768 bf16 im2col
  float* tokens = dtt;                              // 3136x384 f32
  float* mx     = dtt + (size_t)NROW * D_MODEL;     // 3136x384 f32
  float* hnf    = dtt;                              // head: f32 logmap rows

  // ---- weight conversion (every call) ----
  k_cvt<<<dim3((int)((n_inw / 4 + 255) / 256)), dim3(256), 0, stream>>>(
      in_w, in_wb, (int)(n_inw / 4));
  k_cvt<<<dim3((int)((n_outw / 4 + 255) / 256)), dim3(256), 0, stream>>>(
      out_w, out_wb, (int)(n_outw / 4));
  k_cvt<<<dim3((int)((n_xpw / 4 + 255) / 256)), dim3(256), 0, stream>>>(
      xp_w, xp_wb, (int)(n_xpw / 4));
  k_cvt<<<dim3((int)((n_dtw / 4 + 255) / 256)), dim3(256), 0, stream>>>(
      dt_w, dt_wb, (int)(n_dtw / 4));
  k_cvt<<<dim3((int)((n_pw / 4 + 255) / 256)), dim3(256), 0, stream>>>(
      patch_w, p_wb, (int)(n_pw / 4));
  k_cvt<<<dim3((int)((n_hw / 4 + 255) / 256)), dim3(256), 0, stream>>>(
      hyp_w, h_wb, (int)(n_hw / 4));

  // ---- stem ----
  k_im2col<<<dim3((NROW * 768) / 256), dim3(256), 0, stream>>>(x, P_bf);
  k_gemm_bb<<<dim3(NROW / 64, 6), dim3(256), 0, stream>>>(
      P_bf, p_wb, patch_b, tokens, nullptr, 768, 768, D_MODEL, 0, D_MODEL, 0,
      0);
  k_stem_a<<<dim3(NROW), dim3(128), 0, stream>>>(tokens, hn_bf, xn);
  k_gemm_bb<<<dim3(NROW / 64, 6), dim3(256), 0, stream>>>(
      hn_bf, h_wb, nullptr, mx, nullptr, D_MODEL, D_MODEL, D_MODEL, 0, D_MODEL,
      0, 0);
  k_stem_b<<<dim3(NROW), dim3(128), 0, stream>>>(mx, xn, hyp_b, pe_gamma,
                                                 pe_beta, pos, hidden);
  // ---- layers ----
  for (int i = 0; i < NDEPTH; i++) {
    k_resln<<<dim3(NROW / 4), dim3(256), 0, stream>>>(
        hidden, resid, resid, gamma + (size_t)i * D_MODEL,
        beta + (size_t)i * D_MODEL, hn_bf, nullptr, i == 0 ? 1 : 0, 0);
    // in_proj (z-half gets SiLU fused), bf16 out [r, 1536]
    k_gemm_bb<<<dim3(NROW / 64, 24), dim3(256), 0, stream>>>(
        hn_bf, in_wb + (size_t)i * 2 * D_INNER * D_MODEL, nullptr, xz_bf,
        nullptr, D_MODEL, D_MODEL, 2 * D_INNER, 0, 2 * D_INNER, 2, 1);
    // conv + silu -> ut (transposed) AND u_bf (normal)
    k_convt<<<dim3(12, 4, BSZ), dim3(256), 0, stream>>>(
        xz_bf, conv_w + (size_t)i * D_INNER * 4, conv_b + (size_t)i * D_INNER,
        ut, u_bf);
    // x_proj: A = u_bf (coalesced), out dbl normal + dblt transposed
    k_gemm_bb<<<dim3(NROW / 64, 1), dim3(256), 0, stream>>>(
        u_bf, xp_wb + (size_t)i * NXP * D_INNER, nullptr, dbl_n, dblt, D_INNER,
        D_INNER, NXP, NROW, NXP, 0, 1);
    // dt_proj: A = dbl_n (K=24 tail), softplus, out dtt f32 transposed
    k_gemm_bb<<<dim3(NROW / 64, 12), dim3(256), 0, stream>>>(
        dbl_n, dt_wb + (size_t)i * D_INNER * DT_RANK,
        dt_bias + (size_t)i * D_INNER, nullptr, dtt, DT_RANK, NXP, 0, NROW,
        D_INNER, 1, 0);
    // parallel scan -> yt = y + D*u (transposed)
    k_pscan<<<dim3(D_INNER, BSZ), dim3(256), 0, stream>>>(
        dtt, ut, dblt, A_log + (size_t)i * D_INNER * D_STATE,
        Dp + (size_t)i * D_INNER, yt);
    // transpose + silu(z) gate -> yf [r, 768]
    k_trgate<<<dim3(12, 4, BSZ), dim3(256), 0, stream>>>(yt, xz_bf, yf);
    k_gemm_bb<<<dim3(NROW / 64, 6), dim3(256), 0, stream>>>(
        yf, out_wb + (size_t)i * D_MODEL * D_INNER, nullptr, hidden, nullptr,
        D_INNER, D_INNER, D_MODEL, 0, D_MODEL, 0, 0);
  }
  // ---- head ----
  k_resln<<<dim3(NROW / 4), dim3(256), 0, stream>>>(
      hidden, resid, resid, gamma_f, beta_f, nullptr, hnf, 0, 1);
  k_pool1<<<dim3(BSZ, 14), dim3(128), 0, stream>>>(hnf, partial);
  k_pool2<<<dim3(BSZ), dim3(128), 0, stream>>>(partial, pooled, x2v);
  k_head<<<dim3((NCLS + 255) / 256, BSZ), dim3(256), 0, stream>>>(pooled,
                                                                  protos, x2v,
                                                                  out);
}

// Round 7
// 3133.639 us; speedup vs baseline: 1.7203x; 1.0848x over previous
//
#include <hip/hip_runtime.h>
#include <hip/hip_bf16.h>
#include <math.h>

#define D_MODEL 384
#define D_INNER 768
#define D_STATE 16
#define DT_RANK 24
#define NXP 56          // DT_RANK + 2*D_STATE
#define LTOK 196
#define BSZ 16
#define NROW 3136       // BSZ * LTOK
#define NDEPTH 24
#define NCLS 1000

constexpr float kSqrtC   = 0.70710678118654752440f;
constexpr float kMaxNorm = 0.95f / 0.70710678118654752440f;   // 1.3435029...

typedef unsigned short u16;
typedef short  bf16x8 __attribute__((ext_vector_type(8)));
typedef u16    u16x8  __attribute__((ext_vector_type(8)));
typedef float  f32x4  __attribute__((ext_vector_type(4)));

__device__ __forceinline__ float clampf(float x, float lo, float hi) {
  return fminf(fmaxf(x, lo), hi);
}

// f32 -> bf16 (RNE)
__device__ __forceinline__ u16 f2bf(float f) {
  union { float f; unsigned u; } v; v.f = f;
  return (u16)((v.u + 0x7FFFu + ((v.u >> 16) & 1u)) >> 16);
}
// bf16 -> f32
__device__ __forceinline__ float bf2f(u16 s) {
  union { unsigned u; float f; } v; v.u = ((unsigned)s) << 16;
  return v.f;
}

// ---- fast transcendentals (1e-7-ish rel err; invisible under bf16) --------
__device__ __forceinline__ float fsig(float x) {
  return __fdividef(1.f, 1.f + __expf(-x));
}
__device__ __forceinline__ float fsilu(float x) { return x * fsig(x); }
__device__ __forceinline__ float fsoftplus(float x) {
  return (x > 20.f) ? x : __logf(1.f + __expf(x));
}
__device__ __forceinline__ float ftanh(float x) {
  float e = __expf(2.f * x);
  return __fdividef(e - 1.f, e + 1.f);
}
__device__ __forceinline__ float fatanh(float x) {   // x in [0, 0.95]
  return 0.5f * __logf(__fdividef(1.f + x, 1.f - x));
}

// 64-lane wave reduction (no LDS, no barriers)
__device__ __forceinline__ float waveSum(float v) {
#pragma unroll
  for (int o = 1; o < 64; o <<= 1) v += __shfl_xor(v, o, 64);
  return v;
}

// block=128 sum-reduce with broadcast (stem kernels only).
__device__ __forceinline__ float blockSum128(float v, float* sm) {
#pragma unroll
  for (int o = 32; o > 0; o >>= 1) v += __shfl_down(v, o, 64);
  __syncthreads();
  if ((threadIdx.x & 63) == 0) sm[threadIdx.x >> 6] = v;
  __syncthreads();
  return sm[0] + sm[1];
}

// --------------------------- f32 -> bf16 bulk convert (weights, per call) ---
__global__ __launch_bounds__(256) void k_cvt(const float* __restrict__ s,
                                             u16* __restrict__ d, int n4) {
  int i = blockIdx.x * 256 + threadIdx.x;
  if (i >= n4) return;
  float4 v = ((const float4*)s)[i];
  short4 o = {(short)f2bf(v.x), (short)f2bf(v.y), (short)f2bf(v.z),
              (short)f2bf(v.w)};
  *(short4*)&d[(size_t)i * 4] = o;
}

// ------------------------------------------------- im2col (emit bf16) ------
__global__ __launch_bounds__(256) void k_im2col(const float* __restrict__ x,
                                                u16* __restrict__ P) {
  size_t idx = (size_t)blockIdx.x * 256 + threadIdx.x;
  if (idx >= (size_t)NROW * 768) return;
  int k = (int)(idx % 768);
  int r = (int)(idx / 768);
  int b = r / LTOK, t = r % LTOK;
  int hp = t / 14, wp = t % 14;
  int c = k / 256, rem = k % 256, i = rem / 16, j = rem % 16;
  P[idx] = f2bf(
      x[(((size_t)(b * 3 + c) * 224) + hp * 16 + i) * 224 + wp * 16 + j]);
}

// ------------------------- pure-bf16 MFMA GEMM 64x64: C = A*W^T (+b, act) ---
// A (M,K) bf16 rm stride lda. W (Nv,K) bf16 rm tight. Cn normal [r][cg]
// stride ldc (obf: 1=bf16), Ct transposed [cg][r] stride ldct (obf_t);
// null to skip. act: 0 none, 1 softplus(+bias), 2 silu if cg>=768.
#define LDA 40
__global__ __launch_bounds__(256) void k_gemm_bb(
    const u16* __restrict__ A, const u16* __restrict__ W,
    const float* __restrict__ bias, void* __restrict__ Cn,
    void* __restrict__ Ct, int K, int lda, int ldc, int ldct, int Nv, int act,
    int obf, int obf_t) {
  __shared__ u16 As[64 * LDA];
  __shared__ u16 Ws[64 * LDA];
  const int tid = threadIdx.x;
  const int m0 = blockIdx.x * 64;
  const int n0 = blockIdx.y * 64;
  const int lane = tid & 63;
  const int wave = tid >> 6;
  const int wm = wave & 1, wn = wave >> 1;
  const int lm = lane & 15;
  const int quad = lane >> 4;
  const int srow = tid >> 2;
  const int sseg = tid & 3;

  f32x4 acc[2][2];
#pragma unroll
  for (int i = 0; i < 2; i++)
#pragma unroll
    for (int j = 0; j < 2; j++) acc[i][j] = (f32x4){0.f, 0.f, 0.f, 0.f};

  const u16* rowA = A + (size_t)(m0 + srow) * lda + sseg * 8;
  const int wrow = n0 + srow;
  const u16* rowW = W + (size_t)wrow * K + sseg * 8;
  const bool wvalid = wrow < Nv;

  for (int k0 = 0; k0 < K; k0 += 32) {
    u16x8 av = {0, 0, 0, 0, 0, 0, 0, 0}, wv = {0, 0, 0, 0, 0, 0, 0, 0};
    if (k0 + 32 <= K) {
      av = *(const u16x8*)(rowA + k0);
      if (wvalid) wv = *(const u16x8*)(rowW + k0);
    } else {
#pragma unroll
      for (int kk = 0; kk < 8; kk++) {
        int k = k0 + sseg * 8 + kk;
        if (k < K) {
          av[kk] = rowA[k0 + kk];
          if (wvalid) wv[kk] = rowW[k0 + kk];
        }
      }
    }
    __syncthreads();  // guard LDS reuse from previous iter's reads
    *(u16x8*)&As[srow * LDA + sseg * 8] = av;
    *(u16x8*)&Ws[srow * LDA + sseg * 8] = wv;
    __syncthreads();
    bf16x8 af[2], bfr[2];
#pragma unroll
    for (int i = 0; i < 2; i++) {
      af[i]  = *(bf16x8*)&As[(wm * 32 + i * 16 + lm) * LDA + quad * 8];
      bfr[i] = *(bf16x8*)&Ws[(wn * 32 + i * 16 + lm) * LDA + quad * 8];
    }
#pragma unroll
    for (int i = 0; i < 2; i++)
#pragma unroll
      for (int j = 0; j < 2; j++)
        acc[i][j] = __builtin_amdgcn_mfma_f32_16x16x32_bf16(af[i], bfr[j],
                                                            acc[i][j], 0, 0, 0);
  }
  // epilogue: C/D layout col=lane&15, row=quad*4+reg
#pragma unroll
  for (int i = 0; i < 2; i++) {
#pragma unroll
    for (int j = 0; j < 2; j++) {
      int cg = n0 + wn * 32 + j * 16 + lm;
      if (cg >= Nv) continue;
      float bj = bias ? bias[cg] : 0.f;
      float o[4];
      int rgb = m0 + wm * 32 + i * 16 + quad * 4;
#pragma unroll
      for (int reg = 0; reg < 4; reg++) {
        float v = acc[i][j][reg] + bj;
        if (act == 1) v = fsoftplus(v);
        else if (act == 2 && cg >= 768) v = fsilu(v);
        o[reg] = v;
      }
      if (Cn) {
#pragma unroll
        for (int reg = 0; reg < 4; reg++) {
          if (obf) ((u16*)Cn)[(size_t)(rgb + reg) * ldc + cg] = f2bf(o[reg]);
          else ((float*)Cn)[(size_t)(rgb + reg) * ldc + cg] = o[reg];
        }
      }
      if (Ct) {
        if (obf_t) {
          short4 o4 = {(short)f2bf(o[0]), (short)f2bf(o[1]), (short)f2bf(o[2]),
                       (short)f2bf(o[3])};
          *(short4*)&((u16*)Ct)[(size_t)cg * ldct + rgb] = o4;
        } else {
          float4 o4 = {o[0], o[1], o[2], o[3]};
          *(float4*)&((float*)Ct)[(size_t)cg * ldct + rgb] = o4;
        }
      }
    }
  }
}

// -------------------- 64x128 tile GEMM (K%32==0, N%128==0, no guards) -------
// Used for in_proj. 8 MFMA per thread per k-iter.
__global__ __launch_bounds__(256) void k_gemm_n128(
    const u16* __restrict__ A, const u16* __restrict__ W,
    const float* __restrict__ bias, void* __restrict__ Cn, int K, int lda,
    int ldc, int act, int obf) {
  __shared__ u16 As[64 * LDA];
  __shared__ u16 Ws[128 * LDA];
  const int tid = threadIdx.x;
  const int m0 = blockIdx.x * 64;
  const int n0 = blockIdx.y * 128;
  const int lane = tid & 63;
  const int w = tid >> 6;
  const int lm = lane & 15;
  const int quad = lane >> 4;
  const int srow = tid >> 2;
  const int sseg = tid & 3;
  const int wrow = tid >> 1;
  const int wseg = tid & 1;

  f32x4 acc[4][2];
#pragma unroll
  for (int i = 0; i < 4; i++)
#pragma unroll
    for (int j = 0; j < 2; j++) acc[i][j] = (f32x4){0.f, 0.f, 0.f, 0.f};

  const u16* rowA = A + (size_t)(m0 + srow) * lda + sseg * 8;
  const u16* rowW = W + (size_t)(n0 + wrow) * K + wseg * 16;

  for (int k0 = 0; k0 < K; k0 += 32) {
    u16x8 av = *(const u16x8*)(rowA + k0);
    u16x8 wv0 = *(const u16x8*)(rowW + k0);
    u16x8 wv1 = *(const u16x8*)(rowW + k0 + 8);
    __syncthreads();
    *(u16x8*)&As[srow * LDA + sseg * 8] = av;
    *(u16x8*)&Ws[wrow * LDA + wseg * 16] = wv0;
    *(u16x8*)&Ws[wrow * LDA + wseg * 16 + 8] = wv1;
    __syncthreads();
    bf16x8 af[4], bfr[2];
#pragma unroll
    for (int i = 0; i < 4; i++)
      af[i] = *(bf16x8*)&As[(i * 16 + lm) * LDA + quad * 8];
#pragma unroll
    for (int j = 0; j < 2; j++)
      bfr[j] = *(bf16x8*)&Ws[(w * 32 + j * 16 + lm) * LDA + quad * 8];
#pragma unroll
    for (int i = 0; i < 4; i++)
#pragma unroll
      for (int j = 0; j < 2; j++)
        acc[i][j] = __builtin_amdgcn_mfma_f32_16x16x32_bf16(af[i], bfr[j],
                                                            acc[i][j], 0, 0, 0);
  }
#pragma unroll
  for (int i = 0; i < 4; i++) {
#pragma unroll
    for (int j = 0; j < 2; j++) {
      int cg = n0 + w * 32 + j * 16 + lm;
      float bj = bias ? bias[cg] : 0.f;
      int rgb = m0 + i * 16 + quad * 4;
#pragma unroll
      for (int reg = 0; reg < 4; reg++) {
        float v = acc[i][j][reg] + bj;
        if (act == 1) v = fsoftplus(v);
        else if (act == 2 && cg >= 768) v = fsilu(v);
        if (obf) ((u16*)Cn)[(size_t)(rgb + reg) * ldc + cg] = f2bf(v);
        else ((float*)Cn)[(size_t)(rgb + reg) * ldc + cg] = v;
      }
    }
  }
}

// ------------------ stem a: expmap0(tokens) -> bf16 h + ||h|| ---------------
__global__ __launch_bounds__(128) void k_stem_a(const float* __restrict__ tok,
                                                u16* __restrict__ hb,
                                                float* __restrict__ xn) {
  __shared__ float sm[2];
  const int r = blockIdx.x, tid = threadIdx.x;
  float v[3];
#pragma unroll
  for (int j = 0; j < 3; j++) v[j] = tok[(size_t)r * D_MODEL + tid + j * 128];
  float s = blockSum128(v[0] * v[0] + v[1] * v[1] + v[2] * v[2], sm);
  float n = sqrtf(s + 1e-15f);
  float nc = clampf(n, 1e-8f, 5.f);
  float ke = tanhf(kSqrtC * nc) / (kSqrtC * nc);
  float rn = sqrtf(ke * ke * s + 1e-15f);
  float sc = rn > kMaxNorm ? kMaxNorm / rn : 1.f;
  float kk = ke * sc;
#pragma unroll
  for (int j = 0; j < 3; j++)
    hb[(size_t)r * D_MODEL + tid + j * 128] = f2bf(kk * v[j]);
  if (tid == 0) xn[r] = fmaxf(sqrtf(kk * kk * s + 1e-15f), 1e-8f);
}

// --- stem b: mobius_matvec tail + mobius_add(hyp_b) + hyp_LN + pos + expmap -
__global__ __launch_bounds__(128) void k_stem_b(
    const float* __restrict__ mx, const float* __restrict__ xn,
    const float* __restrict__ hyp_b, const float* __restrict__ pe_g,
    const float* __restrict__ pe_b, const float* __restrict__ pos,
    float* __restrict__ outh) {
  __shared__ float sm[2];
  const int r = blockIdx.x, tid = threadIdx.x;
  const int t = r % LTOK;
  float mv[3], bv[3];
  int dd[3];
#pragma unroll
  for (int j = 0; j < 3; j++) {
    dd[j] = tid + j * 128;
    mv[j] = mx[(size_t)r * D_MODEL + dd[j]];
    bv[j] = hyp_b[dd[j]];
  }
  float smx = blockSum128(mv[0] * mv[0] + mv[1] * mv[1] + mv[2] * mv[2], sm);
  float mxn = fmaxf(sqrtf(smx + 1e-15f), 1e-8f);
  float xnv = xn[r];
  float tt = tanhf(mxn / xnv * atanhf(fminf(kSqrtC * xnv, 1.f - 1e-5f)));
  float kres = tt / (mxn * kSqrtC);
  float res[3];
#pragma unroll
  for (int j = 0; j < 3; j++) res[j] = kres * mv[j];
  float xy = blockSum128(res[0] * bv[0] + res[1] * bv[1] + res[2] * bv[2], sm);
  float y2 = blockSum128(bv[0] * bv[0] + bv[1] * bv[1] + bv[2] * bv[2], sm);
  float x2 = kres * kres * smx;
  float al = 1.f + xy + 0.5f * y2;
  float be = 1.f - 0.5f * x2;
  float den = fmaxf(1.f + xy + 0.25f * x2 * y2, 1e-15f);
  float h1[3];
#pragma unroll
  for (int j = 0; j < 3; j++) h1[j] = (al * res[j] + be * bv[j]) / den;
  float s1 = blockSum128(h1[0] * h1[0] + h1[1] * h1[1] + h1[2] * h1[2], sm);
  float n1 = sqrtf(s1 + 1e-15f);
  float nc1 = clampf(n1, 1e-8f, kMaxNorm);
  float kl = atanhf(fminf(kSqrtC * nc1, 0.95f)) / (kSqrtC * nc1);
  float tl[3];
#pragma unroll
  for (int j = 0; j < 3; j++) tl[j] = kl * h1[j];
  float mean = blockSum128(tl[0] + tl[1] + tl[2], sm) * (1.f / 384.f);
  float dv = 0.f;
#pragma unroll
  for (int j = 0; j < 3; j++) { float d = tl[j] - mean; dv += d * d; }
  float var = blockSum128(dv, sm) * (1.f / 383.f);
  float inv = 1.f / (sqrtf(var) + 1e-5f);
  float g[3];
#pragma unroll
  for (int j = 0; j < 3; j++)
    g[j] = (tl[j] - mean) * inv * pe_g[dd[j]] + pe_b[dd[j]];
  float sg = blockSum128(g[0] * g[0] + g[1] * g[1] + g[2] * g[2], sm);
  float ng = sqrtf(sg + 1e-15f);
  float nc2 = clampf(ng, 1e-8f, 5.f);
  float ke = tanhf(kSqrtC * nc2) / (kSqrtC * nc2);
  float rn = sqrtf(ke * ke * sg + 1e-15f);
  float sc = rn > kMaxNorm ? kMaxNorm / rn : 1.f;
  float kk = ke * sc;
  float s2 = kk * kk * sg;
  float n3 = sqrtf(s2 + 1e-15f);
  float nc3 = clampf(n3, 1e-8f, kMaxNorm);
  float kl2 = atanhf(fminf(kSqrtC * nc3, 0.95f)) / (kSqrtC * nc3);
  float v[3];
#pragma unroll
  for (int j = 0; j < 3; j++)
    v[j] = kl2 * kk * g[j] + pos[(size_t)t * D_MODEL + dd[j]];
  float sv = blockSum128(v[0] * v[0] + v[1] * v[1] + v[2] * v[2], sm);
  float nv = sqrtf(sv + 1e-15f);
  float nc4 = clampf(nv, 1e-8f, 5.f);
  float ke2 = tanhf(kSqrtC * nc4) / (kSqrtC * nc4);
  float rn2 = sqrtf(ke2 * ke2 * sv + 1e-15f);
  float sc2 = rn2 > kMaxNorm ? kMaxNorm / rn2 : 1.f;
#pragma unroll
  for (int j = 0; j < 3; j++)
    outh[(size_t)r * D_MODEL + dd[j]] = ke2 * sc2 * v[j];
}

// --- residual accumulate + hyp_layernorm, one wave per row (no barriers) ----
__global__ __launch_bounds__(256) void k_resln(
    const float* __restrict__ hid, const float* __restrict__ res_in,
    float* __restrict__ res_out, const float* __restrict__ g_,
    const float* __restrict__ b_, u16* __restrict__ out_bf,
    float* __restrict__ out_f, int first, int out_logmap) {
  const int lane = threadIdx.x & 63;
  const int r = blockIdx.x * 4 + (threadIdx.x >> 6);
  float v[6];
  int dd[6];
#pragma unroll
  for (int j = 0; j < 6; j++) {
    dd[j] = lane + j * 64;
    size_t idx = (size_t)r * D_MODEL + dd[j];
    v[j] = hid[idx] + (first ? 0.f : res_in[idx]);
    res_out[idx] = v[j];
  }
  float ss = 0.f;
#pragma unroll
  for (int j = 0; j < 6; j++) ss += v[j] * v[j];
  float s = waveSum(ss);
  float n = sqrtf(s + 1e-15f);
  float nc = clampf(n, 1e-8f, kMaxNorm);
  float kl = fatanh(fminf(kSqrtC * nc, 0.95f)) / (kSqrtC * nc);
  float t[6];
  float ts = 0.f;
#pragma unroll
  for (int j = 0; j < 6; j++) { t[j] = kl * v[j]; ts += t[j]; }
  float mean = waveSum(ts) * (1.f / 384.f);
  float dv = 0.f;
#pragma unroll
  for (int j = 0; j < 6; j++) { float d = t[j] - mean; dv += d * d; }
  float var = waveSum(dv) * (1.f / 383.f);
  float inv = 1.f / (sqrtf(var) + 1e-5f);
  float g[6];
  float gs = 0.f;
#pragma unroll
  for (int j = 0; j < 6; j++) {
    g[j] = (t[j] - mean) * inv * g_[dd[j]] + b_[dd[j]];
    gs += g[j] * g[j];
  }
  float sg = waveSum(gs);
  float ng = sqrtf(sg + 1e-15f);
  float nc2 = clampf(ng, 1e-8f, 5.f);
  float ke = ftanh(kSqrtC * nc2) / (kSqrtC * nc2);
  float rn = sqrtf(ke * ke * sg + 1e-15f);
  float sc = rn > kMaxNorm ? kMaxNorm / rn : 1.f;
  float kk = ke * sc;
  if (!out_logmap) {
#pragma unroll
    for (int j = 0; j < 6; j++)
      out_bf[(size_t)r * D_MODEL + dd[j]] = f2bf(kk * g[j]);
  } else {
    float s2 = kk * kk * sg;
    float n3 = sqrtf(s2 + 1e-15f);
    float nc3 = clampf(n3, 1e-8f, kMaxNorm);
    float kl2 = fatanh(fminf(kSqrtC * nc3, 0.95f)) / (kSqrtC * nc3);
#pragma unroll
    for (int j = 0; j < 6; j++)
      out_f[(size_t)r * D_MODEL + dd[j]] = kl2 * kk * g[j];
  }
}

// -- conv1d(k=4, causal) + SiLU, tiled; writes u transposed AND normal -------
__global__ __launch_bounds__(256) void k_convt(const u16* __restrict__ xz,
                                               const float* __restrict__ cw,
                                               const float* __restrict__ cb,
                                               u16* __restrict__ ut,
                                               u16* __restrict__ un) {
  __shared__ u16 sx[52][68];
  __shared__ u16 su2[49][68];
  const int d0 = blockIdx.x * 64;
  const int l0 = blockIdx.y * 49;
  const int b = blockIdx.z;
  const int t = threadIdx.x;
#pragma unroll
  for (int i = 0; i < 4; i++) {
    int idx = t + i * 256;
    if (idx < 832) {
      int row = idx >> 4, seg = idx & 15;
      int l = l0 - 3 + row;
      short4 v = {0, 0, 0, 0};
      if (l >= 0) {
        const u16* p = xz + (size_t)(b * LTOK + l) * (2 * D_INNER) + d0 + seg * 4;
        v = *(const short4*)p;
      }
      *(short4*)&sx[row][seg * 4] = v;
    }
  }
  __syncthreads();
  const int dl = t & 63, lg = t >> 6;
  const int d = d0 + dl;
  const float c0 = cw[d * 4], c1 = cw[d * 4 + 1], c2 = cw[d * 4 + 2],
              c3 = cw[d * 4 + 3];
  const float bb = cb[d];
  for (int l = lg; l < 49; l += 4) {
    float acc = bb;
    acc = fmaf(c0, bf2f(sx[l + 0][dl]), acc);
    acc = fmaf(c1, bf2f(sx[l + 1][dl]), acc);
    acc = fmaf(c2, bf2f(sx[l + 2][dl]), acc);
    acc = fmaf(c3, bf2f(sx[l + 3][dl]), acc);
    su2[l][dl] = f2bf(fsilu(acc));
  }
  __syncthreads();
#pragma unroll
  for (int i = 0; i < 13; i++) {
    int idx = t + i * 256;
    if (idx < 3136) {
      int d_ = idx / 49, l_ = idx % 49;
      ut[(size_t)(d0 + d_) * NROW + b * LTOK + l0 + l_] = su2[l_][d_];
    }
  }
#pragma unroll
  for (int i = 0; i < 13; i++) {
    int idx = t + i * 256;
    if (idx < 3136) {
      int l_ = idx >> 6, d_ = idx & 63;
      un[(size_t)(b * LTOK + l0 + l_) * D_INNER + d0 + d_] = su2[l_][d_];
    }
  }
}

// ---------- parallel selective scan v3: f32 B/C, 3 barriers, fast exp -------
// One block per (d, b). Thread (n = t&15, c = t>>4), c<14 active.
__global__ __launch_bounds__(256) void k_pscan(
    const float* __restrict__ dtt, const u16* __restrict__ ut,
    const float* __restrict__ dblt, const float* __restrict__ A_log,
    const float* __restrict__ Dp, u16* __restrict__ yt) {
  __shared__ float sdt[196];
  __shared__ float su[196];
  __shared__ float ssA[14][17];
  __shared__ float ssB[14][17];
  const int d = blockIdx.x, b = blockIdx.y;
  const int t = threadIdx.x;
  const size_t col0 = (size_t)b * LTOK;
  if (t < 196) {
    sdt[t] = dtt[(size_t)d * NROW + col0 + t];
    su[t]  = bf2f(ut[(size_t)d * NROW + col0 + t]);
  }
  const int n = t & 15, c = t >> 4;
  const bool act = t < 224;
  float Breg[14], Creg[14], dA[14], hh[14];
  float a = 0.f;
  if (act) {
    a = -__expf(A_log[(size_t)d * D_STATE + n]);
    // (b*196 + c*14) is even -> float2-aligned
    const float2* Bp =
        (const float2*)(dblt + (size_t)(DT_RANK + n) * NROW + col0 + c * 14);
    const float2* Cp = (const float2*)(dblt +
                                       (size_t)(DT_RANK + D_STATE + n) * NROW +
                                       col0 + c * 14);
#pragma unroll
    for (int j = 0; j < 7; j++) {
      float2 bv = Bp[j], cv = Cp[j];
      Breg[2 * j] = bv.x; Breg[2 * j + 1] = bv.y;
      Creg[2 * j] = cv.x; Creg[2 * j + 1] = cv.y;
    }
  }
  __syncthreads();
  if (act) {
    float h = 0.f, p = 1.f;
#pragma unroll
    for (int j = 0; j < 14; j++) {
      int l = c * 14 + j;
      float dtv = sdt[l];
      float e = __expf(dtv * a);
      h = fmaf(e, h, dtv * Breg[j] * su[l]);
      dA[j] = e;
      hh[j] = h;
      p *= e;
    }
    ssA[c][n] = p;
    ssB[c][n] = h;
  }
  __syncthreads();
  // single-wave serial compose over the 14 chunks (lanes 0..15 of wave 0)
  if (t < 16) {
    float Bprev = ssB[0][t];
#pragma unroll
    for (int c2 = 1; c2 < 14; c2++) {
      Bprev = fmaf(ssA[c2][t], Bprev, ssB[c2][t]);
      ssB[c2][t] = Bprev;
    }
  }
  __syncthreads();
  if (act) {
    float h0 = (c > 0) ? ssB[c - 1][n] : 0.f;
    float yl[14];
    float p = 1.f;
#pragma unroll
    for (int j = 0; j < 14; j++) {
      p *= dA[j];
      float hv = fmaf(p, h0, hh[j]);
      yl[j] = hv * Creg[j];
    }
    // reduce across the 16 n-lanes (contiguous lanes within the wave)
#pragma unroll
    for (int j = 0; j < 14; j++) {
      float y = yl[j];
      y += __shfl_xor(y, 1, 64);
      y += __shfl_xor(y, 2, 64);
      y += __shfl_xor(y, 4, 64);
      y += __shfl_xor(y, 8, 64);
      yl[j] = y;
    }
    if (n == 0) {
      const float Dv = Dp[d];
#pragma unroll
      for (int j = 0; j < 14; j++) {
        int l = c * 14 + j;
        yt[(size_t)d * NROW + col0 + l] = f2bf(fmaf(Dv, su[l], yl[j]));
      }
    }
  }
}

// --------- transpose yt [d][r] -> yf [r][d], fused silu(z) gate -------------
__global__ __launch_bounds__(256) void k_trgate(const u16* __restrict__ yt,
                                                const u16* __restrict__ xz,
                                                u16* __restrict__ yf) {
  __shared__ u16 st[49][68];
  const int d0 = blockIdx.x * 64;
  const int l0 = blockIdx.y * 49;
  const int b = blockIdx.z;
  const int t = threadIdx.x;
#pragma unroll
  for (int i = 0; i < 13; i++) {
    int idx = t + i * 256;
    if (idx < 3136) {
      int d_ = idx / 49, l_ = idx % 49;
      st[l_][d_] = yt[(size_t)(d0 + d_) * NROW + b * LTOK + l0 + l_];
    }
  }
  __syncthreads();
#pragma unroll
  for (int i = 0; i < 13; i++) {
    int idx = t + i * 256;
    if (idx < 3136) {
      int l_ = idx >> 6, d_ = idx & 63;
      size_t r = (size_t)(b * LTOK + l0 + l_);
      float z = bf2f(xz[r * (2 * D_INNER) + D_INNER + d0 + d_]);  // silu'd
      yf[r * D_INNER + d0 + d_] = f2bf(bf2f(st[l_][d_]) * z);
    }
  }
}

// ---------------------- pool phase 1: partial sums over 14-token chunks -----
__global__ __launch_bounds__(128) void k_pool1(const float* __restrict__ tl,
                                               float* __restrict__ partial) {
  const int b = blockIdx.x, g = blockIdx.y, tid = threadIdx.x;
  float m[3] = {0.f, 0.f, 0.f};
  for (int l = g * 14; l < (g + 1) * 14; l++) {
    size_t row = ((size_t)b * LTOK + l) * D_MODEL;
#pragma unroll
    for (int j = 0; j < 3; j++) m[j] += tl[row + tid + j * 128];
  }
#pragma unroll
  for (int j = 0; j < 3; j++)
    partial[((size_t)b * 14 + g) * D_MODEL + tid + j * 128] = m[j];
}

// ------------------ pool phase 2: finalize mean + expmap0 -------------------
__global__ __launch_bounds__(128) void k_pool2(const float* __restrict__ partial,
                                               float* __restrict__ pooled,
                                               float* __restrict__ x2v) {
  __shared__ float sm[2];
  const int b = blockIdx.x, tid = threadIdx.x;
  float m[3] = {0.f, 0.f, 0.f};
  for (int g = 0; g < 14; g++) {
    size_t row = ((size_t)b * 14 + g) * D_MODEL;
#pragma unroll
    for (int j = 0; j < 3; j++) m[j] += partial[row + tid + j * 128];
  }
#pragma unroll
  for (int j = 0; j < 3; j++) m[j] *= (1.f / (float)LTOK);
  float s = blockSum128(m[0] * m[0] + m[1] * m[1] + m[2] * m[2], sm);
  float n = sqrtf(s + 1e-15f);
  float nc = clampf(n, 1e-8f, 5.f);
  float ke = tanhf(kSqrtC * nc) / (kSqrtC * nc);
  float rn = sqrtf(ke * ke * s + 1e-15f);
  float sc = rn > kMaxNorm ? kMaxNorm / rn : 1.f;
  float kk = ke * sc;
  float p[3];
#pragma unroll
  for (int j = 0; j < 3; j++) {
    p[j] = kk * m[j];
    pooled[(size_t)b * D_MODEL + tid + j * 128] = p[j];
  }
  float s2 = blockSum128(p[0] * p[0] + p[1] * p[1] + p[2] * p[2], sm);
  if (tid == 0) x2v[b] = s2;
}

// ------------------- hyperbolic distance head over prototypes ---------------
__global__ __launch_bounds__(256) void k_head(const float* __restrict__ pooled,
                                              const float* __restrict__ protos,
                                              const float* __restrict__ x2v,
                                              float* __restrict__ out) {
  __shared__ float sp[D_MODEL];
  const int b = blockIdx.y;
  const int c = blockIdx.x * 256 + threadIdx.x;
  for (int j = threadIdx.x; j < D_MODEL; j += 256)
    sp[j] = pooled[(size_t)b * D_MODEL + j];
  __syncthreads();
  if (c >= NCLS) return;
  const float* pr = protos + (size_t)c * D_MODEL;
  float dotv = 0.f, y2 = 0.f;
  for (int k = 0; k < D_MODEL; k++) {
    float w = pr[k];
    dotv += sp[k] * w;
    y2 += w * w;
  }
  float x2 = x2v[b];
  float xy = -dotv;
  float al = 1.f + xy + 0.5f * y2;
  float be = 1.f - 0.5f * x2;
  float num2 = al * al * x2 + 2.f * al * be * xy + be * be * y2;
  float den = fmaxf(1.f + xy + 0.25f * x2 * y2, 1e-15f);
  float r2 = num2 / (den * den) + 1e-15f;
  float dn = fminf(kSqrtC * sqrtf(r2), 1.f - 1e-5f);
  out[(size_t)b * NCLS + c] = -(2.f / kSqrtC) * atanhf(dn);
}

// ---------------------------------------------------------------------------
extern "C" void kernel_launch(void* const* d_in, const int* in_sizes, int n_in,
                              void* d_out, int out_size, void* d_ws,
                              size_t ws_size, hipStream_t stream) {
  const float* x        = (const float*)d_in[0];
  const float* patch_w  = (const float*)d_in[1];
  const float* patch_b  = (const float*)d_in[2];
  const float* hyp_w    = (const float*)d_in[3];
  const float* hyp_b    = (const float*)d_in[4];
  const float* pe_gamma = (const float*)d_in[5];
  const float* pe_beta  = (const float*)d_in[6];
  const float* pos      = (const float*)d_in[7];
  const float* in_w     = (const float*)d_in[8];
  const float* conv_w   = (const float*)d_in[9];
  const float* conv_b   = (const float*)d_in[10];
  const float* xp_w     = (const float*)d_in[11];
  const float* dt_w     = (const float*)d_in[12];
  const float* dt_bias  = (const float*)d_in[13];
  const float* A_log    = (const float*)d_in[14];
  const float* Dp       = (const float*)d_in[15];
  const float* out_w    = (const float*)d_in[16];
  const float* gamma    = (const float*)d_in[17];
  const float* beta     = (const float*)d_in[18];
  const float* gamma_f  = (const float*)d_in[19];
  const float* beta_f   = (const float*)d_in[20];
  const float* protos   = (const float*)d_in[21];
  float* out = (float*)d_out;

  // ---- workspace layout ----
  char* cur = (char*)d_ws;
  auto alloc = [&](size_t bytes) {
    char* p = cur;
    cur += (bytes + 255) & ~(size_t)255;
    return (void*)p;
  };
  float* hidden  = (float*)alloc((size_t)NROW * D_MODEL * 4);
  float* resid   = (float*)alloc((size_t)NROW * D_MODEL * 4);
  float* dtt     = (float*)alloc((size_t)D_INNER * NROW * 4);  // dt^T f32
  float* dblt    = (float*)alloc((size_t)64 * NROW * 4);       // dbl^T f32
  float* xn      = (float*)alloc((size_t)NROW * 4);
  float* pooled  = (float*)alloc((size_t)BSZ * D_MODEL * 4);
  float* x2v     = (float*)alloc((size_t)BSZ * 4);
  float* partial = (float*)alloc((size_t)BSZ * 14 * D_MODEL * 4);
  u16* hn_bf  = (u16*)alloc((size_t)NROW * D_MODEL * 2);
  u16* xz_bf  = (u16*)alloc((size_t)NROW * 2 * D_INNER * 2);
  u16* dbl_n  = (u16*)alloc((size_t)NROW * NXP * 2);           // dbl normal
  u16* ut     = (u16*)alloc((size_t)D_INNER * NROW * 2);       // u^T
  u16* u_bf   = (u16*)alloc((size_t)NROW * D_INNER * 2);       // u normal
  u16* yt     = (u16*)alloc((size_t)D_INNER * NROW * 2);       // y^T
  u16* yf     = (u16*)alloc((size_t)NROW * D_INNER * 2);
  // bf16 weights
  const size_t n_inw  = (size_t)NDEPTH * 2 * D_INNER * D_MODEL;
  const size_t n_outw = (size_t)NDEPTH * D_MODEL * D_INNER;
  const size_t n_xpw  = (size_t)NDEPTH * NXP * D_INNER;
  const size_t n_dtw  = (size_t)NDEPTH * D_INNER * DT_RANK;
  const size_t n_pw   = (size_t)D_MODEL * 768;
  const size_t n_hw   = (size_t)D_MODEL * D_MODEL;
  u16* in_wb  = (u16*)alloc(n_inw * 2);
  u16* out_wb = (u16*)alloc(n_outw * 2);
  u16* xp_wb  = (u16*)alloc(n_xpw * 2);
  u16* dt_wb  = (u16*)alloc(n_dtw * 2);
  u16* p_wb   = (u16*)alloc(n_pw * 2);
  u16* h_wb   = (u16*)alloc(n_hw * 2);
  // stem/head aliases over dead regions
  u16* P_bf     = ut;                               // 3136x768 bf16 im2col
  float* tokens = dtt;                              // 3136x384 f32
  float* mx     = dtt + (size_t)NROW * D_MODEL;     // 3136x384 f32
  float* hnf    = dtt;                              // head: f32 logmap rows

  // ---- weight conversion (every call) ----
  k_cvt<<<dim3((int)((n_inw / 4 + 255) / 256)), dim3(256), 0, stream>>>(
      in_w, in_wb, (int)(n_inw / 4));
  k_cvt<<<dim3((int)((n_outw / 4 + 255) / 256)), dim3(256), 0, stream>>>(
      out_w, out_wb, (int)(n_outw / 4));
  k_cvt<<<dim3((int)((n_xpw / 4 + 255) / 256)), dim3(256), 0, stream>>>(
      xp_w, xp_wb, (int)(n_xpw / 4));
  k_cvt<<<dim3((int)((n_dtw / 4 + 255) / 256)), dim3(256), 0, stream>>>(
      dt_w, dt_wb, (int)(n_dtw / 4));
  k_cvt<<<dim3((int)((n_pw / 4 + 255) / 256)), dim3(256), 0, stream>>>(
      patch_w, p_wb, (int)(n_pw / 4));
  k_cvt<<<dim3((int)((n_hw / 4 + 255) / 256)), dim3(256), 0, stream>>>(
      hyp_w, h_wb, (int)(n_hw / 4));

  // ---- stem ----
  k_im2col<<<dim3((NROW * 768) / 256), dim3(256), 0, stream>>>(x, P_bf);
  k_gemm_bb<<<dim3(NROW / 64, 6), dim3(256), 0, stream>>>(
      P_bf, p_wb, patch_b, tokens, nullptr, 768, 768, D_MODEL, 0, D_MODEL, 0,
      0, 0);
  k_stem_a<<<dim3(NROW), dim3(128), 0, stream>>>(tokens, hn_bf, xn);
  k_gemm_bb<<<dim3(NROW / 64, 6), dim3(256), 0, stream>>>(
      hn_bf, h_wb, nullptr, mx, nullptr, D_MODEL, D_MODEL, D_MODEL, 0, D_MODEL,
      0, 0, 0);
  k_stem_b<<<dim3(NROW), dim3(128), 0, stream>>>(mx, xn, hyp_b, pe_gamma,
                                                 pe_beta, pos, hidden);
  // ---- layers ----
  for (int i = 0; i < NDEPTH; i++) {
    k_resln<<<dim3(NROW / 4), dim3(256), 0, stream>>>(
        hidden, resid, resid, gamma + (size_t)i * D_MODEL,
        beta + (size_t)i * D_MODEL, hn_bf, nullptr, i == 0 ? 1 : 0, 0);
    // in_proj (z-half gets SiLU fused), bf16 out [r, 1536] — 64x128 tiles
    k_gemm_n128<<<dim3(NROW / 64, (2 * D_INNER) / 128), dim3(256), 0, stream>>>(
        hn_bf, in_wb + (size_t)i * 2 * D_INNER * D_MODEL, nullptr, xz_bf,
        D_MODEL, D_MODEL, 2 * D_INNER, 2, 1);
    // conv + silu -> ut (transposed) AND u_bf (normal)
    k_convt<<<dim3(12, 4, BSZ), dim3(256), 0, stream>>>(
        xz_bf, conv_w + (size_t)i * D_INNER * 4, conv_b + (size_t)i * D_INNER,
        ut, u_bf);
    // x_proj: A = u_bf (coalesced); out dbl_n (bf16) + dblt (f32 transposed)
    k_gemm_bb<<<dim3(NROW / 64, 1), dim3(256), 0, stream>>>(
        u_bf, xp_wb + (size_t)i * NXP * D_INNER, nullptr, dbl_n, dblt, D_INNER,
        D_INNER, NXP, NROW, NXP, 0, 1, 0);
    // dt_proj: A = dbl_n (K=24 tail), softplus, out dtt f32 transposed
    k_gemm_bb<<<dim3(NROW / 64, 12), dim3(256), 0, stream>>>(
        dbl_n, dt_wb + (size_t)i * D_INNER * DT_RANK,
        dt_bias + (size_t)i * D_INNER, nullptr, dtt, DT_RANK, NXP, 0, NROW,
        D_INNER, 1, 0, 0);
    // parallel scan -> yt = y + D*u (transposed)
    k_pscan<<<dim3(D_INNER, BSZ), dim3(256), 0, stream>>>(
        dtt, ut, dblt, A_log + (size_t)i * D_INNER * D_STATE,
        Dp + (size_t)i * D_INNER, yt);
    // transpose + silu(z) gate -> yf [r, 768]
    k_trgate<<<dim3(12, 4, BSZ), dim3(256), 0, stream>>>(yt, xz_bf, yf);
    k_gemm_bb<<<dim3(NROW / 64, 6), dim3(256), 0, stream>>>(
        yf, out_wb + (size_t)i * D_MODEL * D_INNER, nullptr, hidden, nullptr,
        D_INNER, D_INNER, D_MODEL, 0, D_MODEL, 0, 0, 0);
  }
  // ---- head ----
  k_resln<<<dim3(NROW / 4), dim3(256), 0, stream>>>(
      hidden, resid, resid, gamma_f, beta_f, nullptr, hnf, 0, 1);
  k_pool1<<<dim3(BSZ, 14), dim3(128), 0, stream>>>(hnf, partial);
  k_pool2<<<dim3(BSZ), dim3(128), 0, stream>>>(partial, pooled, x2v);
  k_head<<<dim3((NCLS + 255) / 256, BSZ), dim3(256), 0, stream>>>(pooled,
                                                                  protos, x2v,
                                                                  out);
}

// Round 8
// 2490.303 us; speedup vs baseline: 2.1647x; 1.2583x over previous
//
#include <hip/hip_runtime.h>
#include <hip/hip_bf16.h>
#include <math.h>

#define D_MODEL 384
#define D_INNER 768
#define D_STATE 16
#define DT_RANK 24
#define NXP 56          // DT_RANK + 2*D_STATE
#define LTOK 196
#define BSZ 16
#define NROW 3136       // BSZ * LTOK
#define NDEPTH 24
#define NCLS 1000

constexpr float kSqrtC   = 0.70710678118654752440f;
constexpr float kMaxNorm = 0.95f / 0.70710678118654752440f;   // 1.3435029...

typedef unsigned short u16;
typedef short  bf16x8 __attribute__((ext_vector_type(8)));
typedef u16    u16x8  __attribute__((ext_vector_type(8)));
typedef float  f32x4  __attribute__((ext_vector_type(4)));

__device__ __forceinline__ float clampf(float x, float lo, float hi) {
  return fminf(fmaxf(x, lo), hi);
}

// f32 -> bf16 (RNE)
__device__ __forceinline__ u16 f2bf(float f) {
  union { float f; unsigned u; } v; v.f = f;
  return (u16)((v.u + 0x7FFFu + ((v.u >> 16) & 1u)) >> 16);
}
// bf16 -> f32
__device__ __forceinline__ float bf2f(u16 s) {
  union { unsigned u; float f; } v; v.u = ((unsigned)s) << 16;
  return v.f;
}

// ---- fast transcendentals (1e-7-ish rel err; invisible under bf16) --------
__device__ __forceinline__ float fsig(float x) {
  return __fdividef(1.f, 1.f + __expf(-x));
}
__device__ __forceinline__ float fsilu(float x) { return x * fsig(x); }
__device__ __forceinline__ float fsoftplus(float x) {
  return (x > 20.f) ? x : __logf(1.f + __expf(x));
}
__device__ __forceinline__ float ftanh(float x) {
  float e = __expf(2.f * x);
  return __fdividef(e - 1.f, e + 1.f);
}
__device__ __forceinline__ float fatanh(float x) {   // x in [0, 0.95]
  return 0.5f * __logf(__fdividef(1.f + x, 1.f - x));
}

// 64-lane wave reduction (no LDS, no barriers)
__device__ __forceinline__ float waveSum(float v) {
#pragma unroll
  for (int o = 1; o < 64; o <<= 1) v += __shfl_xor(v, o, 64);
  return v;
}

// block=128 sum-reduce with broadcast (stem kernels only).
__device__ __forceinline__ float blockSum128(float v, float* sm) {
#pragma unroll
  for (int o = 32; o > 0; o >>= 1) v += __shfl_down(v, o, 64);
  __syncthreads();
  if ((threadIdx.x & 63) == 0) sm[threadIdx.x >> 6] = v;
  __syncthreads();
  return sm[0] + sm[1];
}

// --------------------------- f32 -> bf16 bulk convert (weights, per call) ---
__global__ __launch_bounds__(256) void k_cvt(const float* __restrict__ s,
                                             u16* __restrict__ d, int n4) {
  int i = blockIdx.x * 256 + threadIdx.x;
  if (i >= n4) return;
  float4 v = ((const float4*)s)[i];
  short4 o = {(short)f2bf(v.x), (short)f2bf(v.y), (short)f2bf(v.z),
              (short)f2bf(v.w)};
  *(short4*)&d[(size_t)i * 4] = o;
}

// ------------------------------------------------- im2col (emit bf16) ------
__global__ __launch_bounds__(256) void k_im2col(const float* __restrict__ x,
                                                u16* __restrict__ P) {
  size_t idx = (size_t)blockIdx.x * 256 + threadIdx.x;
  if (idx >= (size_t)NROW * 768) return;
  int k = (int)(idx % 768);
  int r = (int)(idx / 768);
  int b = r / LTOK, t = r % LTOK;
  int hp = t / 14, wp = t % 14;
  int c = k / 256, rem = k % 256, i = rem / 16, j = rem % 16;
  P[idx] = f2bf(
      x[(((size_t)(b * 3 + c) * 224) + hp * 16 + i) * 224 + wp * 16 + j]);
}

// ------------------------- pure-bf16 MFMA GEMM 64x64: C = A*W^T (+b, act) ---
// A (M,K) bf16 rm stride lda. W (Nv,K) bf16 rm tight. Cn normal [r][cg]
// stride ldc (obf: 1=bf16), Ct transposed [cg][r] stride ldct (obf_t);
// null to skip. act: 0 none, 1 softplus(+bias), 2 silu if cg>=768.
#define LDA 40
__global__ __launch_bounds__(256) void k_gemm_bb(
    const u16* __restrict__ A, const u16* __restrict__ W,
    const float* __restrict__ bias, void* __restrict__ Cn,
    void* __restrict__ Ct, int K, int lda, int ldc, int ldct, int Nv, int act,
    int obf, int obf_t) {
  __shared__ u16 As[64 * LDA];
  __shared__ u16 Ws[64 * LDA];
  const int tid = threadIdx.x;
  const int m0 = blockIdx.x * 64;
  const int n0 = blockIdx.y * 64;
  const int lane = tid & 63;
  const int wave = tid >> 6;
  const int wm = wave & 1, wn = wave >> 1;
  const int lm = lane & 15;
  const int quad = lane >> 4;
  const int srow = tid >> 2;
  const int sseg = tid & 3;

  f32x4 acc[2][2];
#pragma unroll
  for (int i = 0; i < 2; i++)
#pragma unroll
    for (int j = 0; j < 2; j++) acc[i][j] = (f32x4){0.f, 0.f, 0.f, 0.f};

  const u16* rowA = A + (size_t)(m0 + srow) * lda + sseg * 8;
  const int wrow = n0 + srow;
  const u16* rowW = W + (size_t)wrow * K + sseg * 8;
  const bool wvalid = wrow < Nv;

  for (int k0 = 0; k0 < K; k0 += 32) {
    u16x8 av = {0, 0, 0, 0, 0, 0, 0, 0}, wv = {0, 0, 0, 0, 0, 0, 0, 0};
    if (k0 + 32 <= K) {
      av = *(const u16x8*)(rowA + k0);
      if (wvalid) wv = *(const u16x8*)(rowW + k0);
    } else {
#pragma unroll
      for (int kk = 0; kk < 8; kk++) {
        int k = k0 + sseg * 8 + kk;
        if (k < K) {
          av[kk] = rowA[k0 + kk];
          if (wvalid) wv[kk] = rowW[k0 + kk];
        }
      }
    }
    __syncthreads();  // guard LDS reuse from previous iter's reads
    *(u16x8*)&As[srow * LDA + sseg * 8] = av;
    *(u16x8*)&Ws[srow * LDA + sseg * 8] = wv;
    __syncthreads();
    bf16x8 af[2], bfr[2];
#pragma unroll
    for (int i = 0; i < 2; i++) {
      af[i]  = *(bf16x8*)&As[(wm * 32 + i * 16 + lm) * LDA + quad * 8];
      bfr[i] = *(bf16x8*)&Ws[(wn * 32 + i * 16 + lm) * LDA + quad * 8];
    }
#pragma unroll
    for (int i = 0; i < 2; i++)
#pragma unroll
      for (int j = 0; j < 2; j++)
        acc[i][j] = __builtin_amdgcn_mfma_f32_16x16x32_bf16(af[i], bfr[j],
                                                            acc[i][j], 0, 0, 0);
  }
  // epilogue: C/D layout col=lane&15, row=quad*4+reg
#pragma unroll
  for (int i = 0; i < 2; i++) {
#pragma unroll
    for (int j = 0; j < 2; j++) {
      int cg = n0 + wn * 32 + j * 16 + lm;
      if (cg >= Nv) continue;
      float bj = bias ? bias[cg] : 0.f;
      float o[4];
      int rgb = m0 + wm * 32 + i * 16 + quad * 4;
#pragma unroll
      for (int reg = 0; reg < 4; reg++) {
        float v = acc[i][j][reg] + bj;
        if (act == 1) v = fsoftplus(v);
        else if (act == 2 && cg >= 768) v = fsilu(v);
        o[reg] = v;
      }
      if (Cn) {
#pragma unroll
        for (int reg = 0; reg < 4; reg++) {
          if (obf) ((u16*)Cn)[(size_t)(rgb + reg) * ldc + cg] = f2bf(o[reg]);
          else ((float*)Cn)[(size_t)(rgb + reg) * ldc + cg] = o[reg];
        }
      }
      if (Ct) {
        if (obf_t) {
          short4 o4 = {(short)f2bf(o[0]), (short)f2bf(o[1]), (short)f2bf(o[2]),
                       (short)f2bf(o[3])};
          *(short4*)&((u16*)Ct)[(size_t)cg * ldct + rgb] = o4;
        } else {
          float4 o4 = {o[0], o[1], o[2], o[3]};
          *(float4*)&((float*)Ct)[(size_t)cg * ldct + rgb] = o4;
        }
      }
    }
  }
}

// -------------------- 64x128 tile GEMM (K%32==0, N%128==0, no guards) -------
// Used for in_proj. 8 MFMA per thread per k-iter.
__global__ __launch_bounds__(256) void k_gemm_n128(
    const u16* __restrict__ A, const u16* __restrict__ W,
    const float* __restrict__ bias, void* __restrict__ Cn, int K, int lda,
    int ldc, int act, int obf) {
  __shared__ u16 As[64 * LDA];
  __shared__ u16 Ws[128 * LDA];
  const int tid = threadIdx.x;
  const int m0 = blockIdx.x * 64;
  const int n0 = blockIdx.y * 128;
  const int lane = tid & 63;
  const int w = tid >> 6;
  const int lm = lane & 15;
  const int quad = lane >> 4;
  const int srow = tid >> 2;
  const int sseg = tid & 3;
  const int wrow = tid >> 1;
  const int wseg = tid & 1;

  f32x4 acc[4][2];
#pragma unroll
  for (int i = 0; i < 4; i++)
#pragma unroll
    for (int j = 0; j < 2; j++) acc[i][j] = (f32x4){0.f, 0.f, 0.f, 0.f};

  const u16* rowA = A + (size_t)(m0 + srow) * lda + sseg * 8;
  const u16* rowW = W + (size_t)(n0 + wrow) * K + wseg * 16;

  for (int k0 = 0; k0 < K; k0 += 32) {
    u16x8 av = *(const u16x8*)(rowA + k0);
    u16x8 wv0 = *(const u16x8*)(rowW + k0);
    u16x8 wv1 = *(const u16x8*)(rowW + k0 + 8);
    __syncthreads();
    *(u16x8*)&As[srow * LDA + sseg * 8] = av;
    *(u16x8*)&Ws[wrow * LDA + wseg * 16] = wv0;
    *(u16x8*)&Ws[wrow * LDA + wseg * 16 + 8] = wv1;
    __syncthreads();
    bf16x8 af[4], bfr[2];
#pragma unroll
    for (int i = 0; i < 4; i++)
      af[i] = *(bf16x8*)&As[(i * 16 + lm) * LDA + quad * 8];
#pragma unroll
    for (int j = 0; j < 2; j++)
      bfr[j] = *(bf16x8*)&Ws[(w * 32 + j * 16 + lm) * LDA + quad * 8];
#pragma unroll
    for (int i = 0; i < 4; i++)
#pragma unroll
      for (int j = 0; j < 2; j++)
        acc[i][j] = __builtin_amdgcn_mfma_f32_16x16x32_bf16(af[i], bfr[j],
                                                            acc[i][j], 0, 0, 0);
  }
#pragma unroll
  for (int i = 0; i < 4; i++) {
#pragma unroll
    for (int j = 0; j < 2; j++) {
      int cg = n0 + w * 32 + j * 16 + lm;
      float bj = bias ? bias[cg] : 0.f;
      int rgb = m0 + i * 16 + quad * 4;
#pragma unroll
      for (int reg = 0; reg < 4; reg++) {
        float v = acc[i][j][reg] + bj;
        if (act == 1) v = fsoftplus(v);
        else if (act == 2 && cg >= 768) v = fsilu(v);
        if (obf) ((u16*)Cn)[(size_t)(rgb + reg) * ldc + cg] = f2bf(v);
        else ((float*)Cn)[(size_t)(rgb + reg) * ldc + cg] = v;
      }
    }
  }
}

// ------------------ stem a: expmap0(tokens) -> bf16 h + ||h|| ---------------
__global__ __launch_bounds__(128) void k_stem_a(const float* __restrict__ tok,
                                                u16* __restrict__ hb,
                                                float* __restrict__ xn) {
  __shared__ float sm[2];
  const int r = blockIdx.x, tid = threadIdx.x;
  float v[3];
#pragma unroll
  for (int j = 0; j < 3; j++) v[j] = tok[(size_t)r * D_MODEL + tid + j * 128];
  float s = blockSum128(v[0] * v[0] + v[1] * v[1] + v[2] * v[2], sm);
  float n = sqrtf(s + 1e-15f);
  float nc = clampf(n, 1e-8f, 5.f);
  float ke = tanhf(kSqrtC * nc) / (kSqrtC * nc);
  float rn = sqrtf(ke * ke * s + 1e-15f);
  float sc = rn > kMaxNorm ? kMaxNorm / rn : 1.f;
  float kk = ke * sc;
#pragma unroll
  for (int j = 0; j < 3; j++)
    hb[(size_t)r * D_MODEL + tid + j * 128] = f2bf(kk * v[j]);
  if (tid == 0) xn[r] = fmaxf(sqrtf(kk * kk * s + 1e-15f), 1e-8f);
}

// --- stem b: mobius_matvec tail + mobius_add(hyp_b) + hyp_LN + pos + expmap -
__global__ __launch_bounds__(128) void k_stem_b(
    const float* __restrict__ mx, const float* __restrict__ xn,
    const float* __restrict__ hyp_b, const float* __restrict__ pe_g,
    const float* __restrict__ pe_b, const float* __restrict__ pos,
    float* __restrict__ outh) {
  __shared__ float sm[2];
  const int r = blockIdx.x, tid = threadIdx.x;
  const int t = r % LTOK;
  float mv[3], bv[3];
  int dd[3];
#pragma unroll
  for (int j = 0; j < 3; j++) {
    dd[j] = tid + j * 128;
    mv[j] = mx[(size_t)r * D_MODEL + dd[j]];
    bv[j] = hyp_b[dd[j]];
  }
  float smx = blockSum128(mv[0] * mv[0] + mv[1] * mv[1] + mv[2] * mv[2], sm);
  float mxn = fmaxf(sqrtf(smx + 1e-15f), 1e-8f);
  float xnv = xn[r];
  float tt = tanhf(mxn / xnv * atanhf(fminf(kSqrtC * xnv, 1.f - 1e-5f)));
  float kres = tt / (mxn * kSqrtC);
  float res[3];
#pragma unroll
  for (int j = 0; j < 3; j++) res[j] = kres * mv[j];
  float xy = blockSum128(res[0] * bv[0] + res[1] * bv[1] + res[2] * bv[2], sm);
  float y2 = blockSum128(bv[0] * bv[0] + bv[1] * bv[1] + bv[2] * bv[2], sm);
  float x2 = kres * kres * smx;
  float al = 1.f + xy + 0.5f * y2;
  float be = 1.f - 0.5f * x2;
  float den = fmaxf(1.f + xy + 0.25f * x2 * y2, 1e-15f);
  float h1[3];
#pragma unroll
  for (int j = 0; j < 3; j++) h1[j] = (al * res[j] + be * bv[j]) / den;
  float s1 = blockSum128(h1[0] * h1[0] + h1[1] * h1[1] + h1[2] * h1[2], sm);
  float n1 = sqrtf(s1 + 1e-15f);
  float nc1 = clampf(n1, 1e-8f, kMaxNorm);
  float kl = atanhf(fminf(kSqrtC * nc1, 0.95f)) / (kSqrtC * nc1);
  float tl[3];
#pragma unroll
  for (int j = 0; j < 3; j++) tl[j] = kl * h1[j];
  float mean = blockSum128(tl[0] + tl[1] + tl[2], sm) * (1.f / 384.f);
  float dv = 0.f;
#pragma unroll
  for (int j = 0; j < 3; j++) { float d = tl[j] - mean; dv += d * d; }
  float var = blockSum128(dv, sm) * (1.f / 383.f);
  float inv = 1.f / (sqrtf(var) + 1e-5f);
  float g[3];
#pragma unroll
  for (int j = 0; j < 3; j++)
    g[j] = (tl[j] - mean) * inv * pe_g[dd[j]] + pe_b[dd[j]];
  float sg = blockSum128(g[0] * g[0] + g[1] * g[1] + g[2] * g[2], sm);
  float ng = sqrtf(sg + 1e-15f);
  float nc2 = clampf(ng, 1e-8f, 5.f);
  float ke = tanhf(kSqrtC * nc2) / (kSqrtC * nc2);
  float rn = sqrtf(ke * ke * sg + 1e-15f);
  float sc = rn > kMaxNorm ? kMaxNorm / rn : 1.f;
  float kk = ke * sc;
  float s2 = kk * kk * sg;
  float n3 = sqrtf(s2 + 1e-15f);
  float nc3 = clampf(n3, 1e-8f, kMaxNorm);
  float kl2 = atanhf(fminf(kSqrtC * nc3, 0.95f)) / (kSqrtC * nc3);
  float v[3];
#pragma unroll
  for (int j = 0; j < 3; j++)
    v[j] = kl2 * kk * g[j] + pos[(size_t)t * D_MODEL + dd[j]];
  float sv = blockSum128(v[0] * v[0] + v[1] * v[1] + v[2] * v[2], sm);
  float nv = sqrtf(sv + 1e-15f);
  float nc4 = clampf(nv, 1e-8f, 5.f);
  float ke2 = tanhf(kSqrtC * nc4) / (kSqrtC * nc4);
  float rn2 = sqrtf(ke2 * ke2 * sv + 1e-15f);
  float sc2 = rn2 > kMaxNorm ? kMaxNorm / rn2 : 1.f;
#pragma unroll
  for (int j = 0; j < 3; j++)
    outh[(size_t)r * D_MODEL + dd[j]] = ke2 * sc2 * v[j];
}

// --- residual accumulate + hyp_layernorm, one wave per row (no barriers) ----
__global__ __launch_bounds__(256) void k_resln(
    const float* __restrict__ hid, const float* __restrict__ res_in,
    float* __restrict__ res_out, const float* __restrict__ g_,
    const float* __restrict__ b_, u16* __restrict__ out_bf,
    float* __restrict__ out_f, int first, int out_logmap) {
  const int lane = threadIdx.x & 63;
  const int r = blockIdx.x * 4 + (threadIdx.x >> 6);
  float v[6];
  int dd[6];
#pragma unroll
  for (int j = 0; j < 6; j++) {
    dd[j] = lane + j * 64;
    size_t idx = (size_t)r * D_MODEL + dd[j];
    v[j] = hid[idx] + (first ? 0.f : res_in[idx]);
    res_out[idx] = v[j];
  }
  float ss = 0.f;
#pragma unroll
  for (int j = 0; j < 6; j++) ss += v[j] * v[j];
  float s = waveSum(ss);
  float n = sqrtf(s + 1e-15f);
  float nc = clampf(n, 1e-8f, kMaxNorm);
  float kl = fatanh(fminf(kSqrtC * nc, 0.95f)) / (kSqrtC * nc);
  float t[6];
  float ts = 0.f;
#pragma unroll
  for (int j = 0; j < 6; j++) { t[j] = kl * v[j]; ts += t[j]; }
  float mean = waveSum(ts) * (1.f / 384.f);
  float dv = 0.f;
#pragma unroll
  for (int j = 0; j < 6; j++) { float d = t[j] - mean; dv += d * d; }
  float var = waveSum(dv) * (1.f / 383.f);
  float inv = 1.f / (sqrtf(var) + 1e-5f);
  float g[6];
  float gs = 0.f;
#pragma unroll
  for (int j = 0; j < 6; j++) {
    g[j] = (t[j] - mean) * inv * g_[dd[j]] + b_[dd[j]];
    gs += g[j] * g[j];
  }
  float sg = waveSum(gs);
  float ng = sqrtf(sg + 1e-15f);
  float nc2 = clampf(ng, 1e-8f, 5.f);
  float ke = ftanh(kSqrtC * nc2) / (kSqrtC * nc2);
  float rn = sqrtf(ke * ke * sg + 1e-15f);
  float sc = rn > kMaxNorm ? kMaxNorm / rn : 1.f;
  float kk = ke * sc;
  if (!out_logmap) {
#pragma unroll
    for (int j = 0; j < 6; j++)
      out_bf[(size_t)r * D_MODEL + dd[j]] = f2bf(kk * g[j]);
  } else {
    float s2 = kk * kk * sg;
    float n3 = sqrtf(s2 + 1e-15f);
    float nc3 = clampf(n3, 1e-8f, kMaxNorm);
    float kl2 = fatanh(fminf(kSqrtC * nc3, 0.95f)) / (kSqrtC * nc3);
#pragma unroll
    for (int j = 0; j < 6; j++)
      out_f[(size_t)r * D_MODEL + dd[j]] = kl2 * kk * g[j];
  }
}

// -- conv1d(k=4, causal) + SiLU, tiled; writes u transposed AND normal -------
__global__ __launch_bounds__(256) void k_convt(const u16* __restrict__ xz,
                                               const float* __restrict__ cw,
                                               const float* __restrict__ cb,
                                               u16* __restrict__ ut,
                                               u16* __restrict__ un) {
  __shared__ u16 sx[52][68];
  __shared__ u16 su2[49][68];
  const int d0 = blockIdx.x * 64;
  const int l0 = blockIdx.y * 49;
  const int b = blockIdx.z;
  const int t = threadIdx.x;
#pragma unroll
  for (int i = 0; i < 4; i++) {
    int idx = t + i * 256;
    if (idx < 832) {
      int row = idx >> 4, seg = idx & 15;
      int l = l0 - 3 + row;
      short4 v = {0, 0, 0, 0};
      if (l >= 0) {
        const u16* p = xz + (size_t)(b * LTOK + l) * (2 * D_INNER) + d0 + seg * 4;
        v = *(const short4*)p;
      }
      *(short4*)&sx[row][seg * 4] = v;
    }
  }
  __syncthreads();
  const int dl = t & 63, lg = t >> 6;
  const int d = d0 + dl;
  const float c0 = cw[d * 4], c1 = cw[d * 4 + 1], c2 = cw[d * 4 + 2],
              c3 = cw[d * 4 + 3];
  const float bb = cb[d];
  for (int l = lg; l < 49; l += 4) {
    float acc = bb;
    acc = fmaf(c0, bf2f(sx[l + 0][dl]), acc);
    acc = fmaf(c1, bf2f(sx[l + 1][dl]), acc);
    acc = fmaf(c2, bf2f(sx[l + 2][dl]), acc);
    acc = fmaf(c3, bf2f(sx[l + 3][dl]), acc);
    su2[l][dl] = f2bf(fsilu(acc));
  }
  __syncthreads();
#pragma unroll
  for (int i = 0; i < 13; i++) {
    int idx = t + i * 256;
    if (idx < 3136) {
      int d_ = idx / 49, l_ = idx % 49;
      ut[(size_t)(d0 + d_) * NROW + b * LTOK + l0 + l_] = su2[l_][d_];
    }
  }
#pragma unroll
  for (int i = 0; i < 13; i++) {
    int idx = t + i * 256;
    if (idx < 3136) {
      int l_ = idx >> 6, d_ = idx & 63;
      un[(size_t)(b * LTOK + l0 + l_) * D_INNER + d0 + d_] = su2[l_][d_];
    }
  }
}

// ---------- parallel selective scan v4: shfl compose + fused dt_proj --------
// One block per (d, b). Thread (c = t&15, n = t>>4); c<14 active.
// dblt rows 0..23 = dt_r (f32), 24..39 = B, 40..55 = C.
__global__ __launch_bounds__(256) void k_pscan(
    const u16* __restrict__ ut, const float* __restrict__ dblt,
    const float* __restrict__ dt_w, const float* __restrict__ dt_bias,
    const float* __restrict__ A_log, const float* __restrict__ Dp,
    u16* __restrict__ yt) {
  __shared__ float sdt[196];
  __shared__ float su[196];
  __shared__ float sprod[16][197];
  const int d = blockIdx.x, b = blockIdx.y;
  const int t = threadIdx.x;
  const size_t col0 = (size_t)b * LTOK;
  // fused dt_proj: dt[l] = softplus(dt_r[l] . dt_w[d] + dt_bias[d])
  if (t < 196) {
    float acc = dt_bias[d];
#pragma unroll
    for (int k = 0; k < DT_RANK; k++)
      acc = fmaf(dblt[(size_t)k * NROW + col0 + t], dt_w[d * DT_RANK + k], acc);
    sdt[t] = fsoftplus(acc);
    su[t] = bf2f(ut[(size_t)d * NROW + col0 + t]);
  }
  const int c = t & 15, n = t >> 4;
  const bool act = c < 14;
  float Breg[14], Creg[14], dA[14], hh[14];
  const float a = -__expf(A_log[(size_t)d * D_STATE + n]);
  if (act) {
    const float2* Bp =
        (const float2*)(dblt + (size_t)(DT_RANK + n) * NROW + col0 + c * 14);
    const float2* Cp = (const float2*)(
        dblt + (size_t)(DT_RANK + D_STATE + n) * NROW + col0 + c * 14);
#pragma unroll
    for (int j = 0; j < 7; j++) {
      float2 bv = Bp[j], cv = Cp[j];
      Breg[2 * j] = bv.x; Breg[2 * j + 1] = bv.y;
      Creg[2 * j] = cv.x; Creg[2 * j + 1] = cv.y;
    }
  }
  __syncthreads();
  float A = 1.f, B = 0.f;
  if (act) {
    float h = 0.f, p = 1.f;
#pragma unroll
    for (int j = 0; j < 14; j++) {
      int l = c * 14 + j;
      float dtv = sdt[l];
      float e = __expf(dtv * a);
      h = fmaf(e, h, dtv * Breg[j] * su[l]);
      dA[j] = e;
      hh[j] = h;
      p *= e;
    }
    A = p;
    B = h;
  }
  // width-16 segmented inclusive compose-scan over chunks (registers only)
#pragma unroll
  for (int off = 1; off < 16; off <<= 1) {
    float pA = __shfl_up(A, off, 16);
    float pB = __shfl_up(B, off, 16);
    if (c >= off) {
      B = fmaf(A, pB, B);
      A *= pA;
    }
  }
  float h0 = __shfl_up(B, 1, 16);
  if (c == 0) h0 = 0.f;
  if (act) {
    float p = 1.f;
#pragma unroll
    for (int j = 0; j < 14; j++) {
      p *= dA[j];
      sprod[n][c * 14 + j] = fmaf(p, h0, hh[j]) * Creg[j];
    }
  }
  __syncthreads();
  if (t < 196) {
    float y = 0.f;
#pragma unroll
    for (int nn = 0; nn < 16; nn++) y += sprod[nn][t];
    yt[(size_t)d * NROW + col0 + t] = f2bf(fmaf(Dp[d], su[t], y));
  }
}

// --------- transpose yt [d][r] -> yf [r][d], fused silu(z) gate -------------
__global__ __launch_bounds__(256) void k_trgate(const u16* __restrict__ yt,
                                                const u16* __restrict__ xz,
                                                u16* __restrict__ yf) {
  __shared__ u16 st[49][68];
  const int d0 = blockIdx.x * 64;
  const int l0 = blockIdx.y * 49;
  const int b = blockIdx.z;
  const int t = threadIdx.x;
#pragma unroll
  for (int i = 0; i < 13; i++) {
    int idx = t + i * 256;
    if (idx < 3136) {
      int d_ = idx / 49, l_ = idx % 49;
      st[l_][d_] = yt[(size_t)(d0 + d_) * NROW + b * LTOK + l0 + l_];
    }
  }
  __syncthreads();
#pragma unroll
  for (int i = 0; i < 13; i++) {
    int idx = t + i * 256;
    if (idx < 3136) {
      int l_ = idx >> 6, d_ = idx & 63;
      size_t r = (size_t)(b * LTOK + l0 + l_);
      float z = bf2f(xz[r * (2 * D_INNER) + D_INNER + d0 + d_]);  // silu'd
      yf[r * D_INNER + d0 + d_] = f2bf(bf2f(st[l_][d_]) * z);
    }
  }
}

// ---------------------- pool phase 1: partial sums over 14-token chunks -----
__global__ __launch_bounds__(128) void k_pool1(const float* __restrict__ tl,
                                               float* __restrict__ partial) {
  const int b = blockIdx.x, g = blockIdx.y, tid = threadIdx.x;
  float m[3] = {0.f, 0.f, 0.f};
  for (int l = g * 14; l < (g + 1) * 14; l++) {
    size_t row = ((size_t)b * LTOK + l) * D_MODEL;
#pragma unroll
    for (int j = 0; j < 3; j++) m[j] += tl[row + tid + j * 128];
  }
#pragma unroll
  for (int j = 0; j < 3; j++)
    partial[((size_t)b * 14 + g) * D_MODEL + tid + j * 128] = m[j];
}

// ------------------ pool phase 2: finalize mean + expmap0 -------------------
__global__ __launch_bounds__(128) void k_pool2(const float* __restrict__ partial,
                                               float* __restrict__ pooled,
                                               float* __restrict__ x2v) {
  __shared__ float sm[2];
  const int b = blockIdx.x, tid = threadIdx.x;
  float m[3] = {0.f, 0.f, 0.f};
  for (int g = 0; g < 14; g++) {
    size_t row = ((size_t)b * 14 + g) * D_MODEL;
#pragma unroll
    for (int j = 0; j < 3; j++) m[j] += partial[row + tid + j * 128];
  }
#pragma unroll
  for (int j = 0; j < 3; j++) m[j] *= (1.f / (float)LTOK);
  float s = blockSum128(m[0] * m[0] + m[1] * m[1] + m[2] * m[2], sm);
  float n = sqrtf(s + 1e-15f);
  float nc = clampf(n, 1e-8f, 5.f);
  float ke = tanhf(kSqrtC * nc) / (kSqrtC * nc);
  float rn = sqrtf(ke * ke * s + 1e-15f);
  float sc = rn > kMaxNorm ? kMaxNorm / rn : 1.f;
  float kk = ke * sc;
  float p[3];
#pragma unroll
  for (int j = 0; j < 3; j++) {
    p[j] = kk * m[j];
    pooled[(size_t)b * D_MODEL + tid + j * 128] = p[j];
  }
  float s2 = blockSum128(p[0] * p[0] + p[1] * p[1] + p[2] * p[2], sm);
  if (tid == 0) x2v[b] = s2;
}

// ------------------- hyperbolic distance head over prototypes ---------------
__global__ __launch_bounds__(256) void k_head(const float* __restrict__ pooled,
                                              const float* __restrict__ protos,
                                              const float* __restrict__ x2v,
                                              float* __restrict__ out) {
  __shared__ float sp[D_MODEL];
  const int b = blockIdx.y;
  const int c = blockIdx.x * 256 + threadIdx.x;
  for (int j = threadIdx.x; j < D_MODEL; j += 256)
    sp[j] = pooled[(size_t)b * D_MODEL + j];
  __syncthreads();
  if (c >= NCLS) return;
  const float* pr = protos + (size_t)c * D_MODEL;
  float dotv = 0.f, y2 = 0.f;
  for (int k = 0; k < D_MODEL; k++) {
    float w = pr[k];
    dotv += sp[k] * w;
    y2 += w * w;
  }
  float x2 = x2v[b];
  float xy = -dotv;
  float al = 1.f + xy + 0.5f * y2;
  float be = 1.f - 0.5f * x2;
  float num2 = al * al * x2 + 2.f * al * be * xy + be * be * y2;
  float den = fmaxf(1.f + xy + 0.25f * x2 * y2, 1e-15f);
  float r2 = num2 / (den * den) + 1e-15f;
  float dn = fminf(kSqrtC * sqrtf(r2), 1.f - 1e-5f);
  out[(size_t)b * NCLS + c] = -(2.f / kSqrtC) * atanhf(dn);
}

// ---------------------------------------------------------------------------
extern "C" void kernel_launch(void* const* d_in, const int* in_sizes, int n_in,
                              void* d_out, int out_size, void* d_ws,
                              size_t ws_size, hipStream_t stream) {
  const float* x        = (const float*)d_in[0];
  const float* patch_w  = (const float*)d_in[1];
  const float* patch_b  = (const float*)d_in[2];
  const float* hyp_w    = (const float*)d_in[3];
  const float* hyp_b    = (const float*)d_in[4];
  const float* pe_gamma = (const float*)d_in[5];
  const float* pe_beta  = (const float*)d_in[6];
  const float* pos      = (const float*)d_in[7];
  const float* in_w     = (const float*)d_in[8];
  const float* conv_w   = (const float*)d_in[9];
  const float* conv_b   = (const float*)d_in[10];
  const float* xp_w     = (const float*)d_in[11];
  const float* dt_w     = (const float*)d_in[12];
  const float* dt_bias  = (const float*)d_in[13];
  const float* A_log    = (const float*)d_in[14];
  const float* Dp       = (const float*)d_in[15];
  const float* out_w    = (const float*)d_in[16];
  const float* gamma    = (const float*)d_in[17];
  const float* beta     = (const float*)d_in[18];
  const float* gamma_f  = (const float*)d_in[19];
  const float* beta_f   = (const float*)d_in[20];
  const float* protos   = (const float*)d_in[21];
  float* out = (float*)d_out;

  // ---- workspace layout ----
  char* cur = (char*)d_ws;
  auto alloc = [&](size_t bytes) {
    char* p = cur;
    cur += (bytes + 255) & ~(size_t)255;
    return (void*)p;
  };
  float* hidden  = (float*)alloc((size_t)NROW * D_MODEL * 4);
  float* resid   = (float*)alloc((size_t)NROW * D_MODEL * 4);
  float* dblt    = (float*)alloc((size_t)64 * NROW * 4);   // dbl^T f32 (56 rows)
  float* fscr    = (float*)alloc((size_t)NROW * 768 * 4);  // stem/head scratch
  float* xn      = (float*)alloc((size_t)NROW * 4);
  float* pooled  = (float*)alloc((size_t)BSZ * D_MODEL * 4);
  float* x2v     = (float*)alloc((size_t)BSZ * 4);
  float* partial = (float*)alloc((size_t)BSZ * 14 * D_MODEL * 4);
  u16* hn_bf  = (u16*)alloc((size_t)NROW * D_MODEL * 2);
  u16* xz_bf  = (u16*)alloc((size_t)NROW * 2 * D_INNER * 2);
  u16* ut     = (u16*)alloc((size_t)D_INNER * NROW * 2);       // u^T
  u16* u_bf   = (u16*)alloc((size_t)NROW * D_INNER * 2);       // u normal
  u16* yt     = (u16*)alloc((size_t)D_INNER * NROW * 2);       // y^T
  u16* yf     = (u16*)alloc((size_t)NROW * D_INNER * 2);
  // bf16 weights
  const size_t n_inw  = (size_t)NDEPTH * 2 * D_INNER * D_MODEL;
  const size_t n_outw = (size_t)NDEPTH * D_MODEL * D_INNER;
  const size_t n_xpw  = (size_t)NDEPTH * NXP * D_INNER;
  const size_t n_pw   = (size_t)D_MODEL * 768;
  const size_t n_hw   = (size_t)D_MODEL * D_MODEL;
  u16* in_wb  = (u16*)alloc(n_inw * 2);
  u16* out_wb = (u16*)alloc(n_outw * 2);
  u16* xp_wb  = (u16*)alloc(n_xpw * 2);
  u16* p_wb   = (u16*)alloc(n_pw * 2);
  u16* h_wb   = (u16*)alloc(n_hw * 2);
  // stem/head aliases over dead regions
  u16* P_bf     = ut;                               // 3136x768 bf16 im2col
  float* tokens = fscr;                             // 3136x384 f32
  float* mx     = fscr + (size_t)NROW * D_MODEL;    // 3136x384 f32
  float* hnf    = fscr;                             // head: f32 logmap rows

  // ---- weight conversion (every call) ----
  k_cvt<<<dim3((int)((n_inw / 4 + 255) / 256)), dim3(256), 0, stream>>>(
      in_w, in_wb, (int)(n_inw / 4));
  k_cvt<<<dim3((int)((n_outw / 4 + 255) / 256)), dim3(256), 0, stream>>>(
      out_w, out_wb, (int)(n_outw / 4));
  k_cvt<<<dim3((int)((n_xpw / 4 + 255) / 256)), dim3(256), 0, stream>>>(
      xp_w, xp_wb, (int)(n_xpw / 4));
  k_cvt<<<dim3((int)((n_pw / 4 + 255) / 256)), dim3(256), 0, stream>>>(
      patch_w, p_wb, (int)(n_pw / 4));
  k_cvt<<<dim3((int)((n_hw / 4 + 255) / 256)), dim3(256), 0, stream>>>(
      hyp_w, h_wb, (int)(n_hw / 4));

  // ---- stem ----
  k_im2col<<<dim3((NROW * 768) / 256), dim3(256), 0, stream>>>(x, P_bf);
  k_gemm_bb<<<dim3(NROW / 64, 6), dim3(256), 0, stream>>>(
      P_bf, p_wb, patch_b, tokens, nullptr, 768, 768, D_MODEL, 0, D_MODEL, 0,
      0, 0);
  k_stem_a<<<dim3(NROW), dim3(128), 0, stream>>>(tokens, hn_bf, xn);
  k_gemm_bb<<<dim3(NROW / 64, 6), dim3(256), 0, stream>>>(
      hn_bf, h_wb, nullptr, mx, nullptr, D_MODEL, D_MODEL, D_MODEL, 0, D_MODEL,
      0, 0, 0);
  k_stem_b<<<dim3(NROW), dim3(128), 0, stream>>>(mx, xn, hyp_b, pe_gamma,
                                                 pe_beta, pos, hidden);
  // ---- layers ----
  for (int i = 0; i < NDEPTH; i++) {
    k_resln<<<dim3(NROW / 4), dim3(256), 0, stream>>>(
        hidden, resid, resid, gamma + (size_t)i * D_MODEL,
        beta + (size_t)i * D_MODEL, hn_bf, nullptr, i == 0 ? 1 : 0, 0);
    // in_proj (z-half gets SiLU fused), bf16 out [r, 1536] — 64x128 tiles
    k_gemm_n128<<<dim3(NROW / 64, (2 * D_INNER) / 128), dim3(256), 0, stream>>>(
        hn_bf, in_wb + (size_t)i * 2 * D_INNER * D_MODEL, nullptr, xz_bf,
        D_MODEL, D_MODEL, 2 * D_INNER, 2, 1);
    // conv + silu -> ut (transposed) AND u_bf (normal)
    k_convt<<<dim3(12, 4, BSZ), dim3(256), 0, stream>>>(
        xz_bf, conv_w + (size_t)i * D_INNER * 4, conv_b + (size_t)i * D_INNER,
        ut, u_bf);
    // x_proj: A = u_bf (coalesced); out dblt f32 transposed ONLY
    k_gemm_bb<<<dim3(NROW / 64, 1), dim3(256), 0, stream>>>(
        u_bf, xp_wb + (size_t)i * NXP * D_INNER, nullptr, nullptr, dblt,
        D_INNER, D_INNER, 0, NROW, NXP, 0, 0, 0);
    // parallel scan (fused dt_proj) -> yt = y + D*u (transposed)
    k_pscan<<<dim3(D_INNER, BSZ), dim3(256), 0, stream>>>(
        ut, dblt, dt_w + (size_t)i * D_INNER * DT_RANK,
        dt_bias + (size_t)i * D_INNER, A_log + (size_t)i * D_INNER * D_STATE,
        Dp + (size_t)i * D_INNER, yt);
    // transpose + silu(z) gate -> yf [r, 768]
    k_trgate<<<dim3(12, 4, BSZ), dim3(256), 0, stream>>>(yt, xz_bf, yf);
    k_gemm_bb<<<dim3(NROW / 64, 6), dim3(256), 0, stream>>>(
        yf, out_wb + (size_t)i * D_MODEL * D_INNER, nullptr, hidden, nullptr,
        D_INNER, D_INNER, D_MODEL, 0, D_MODEL, 0, 0, 0);
  }
  // ---- head ----
  k_resln<<<dim3(NROW / 4), dim3(256), 0, stream>>>(
      hidden, resid, resid, gamma_f, beta_f, nullptr, hnf, 0, 1);
  k_pool1<<<dim3(BSZ, 14), dim3(128), 0, stream>>>(hnf, partial);
  k_pool2<<<dim3(BSZ), dim3(128), 0, stream>>>(partial, pooled, x2v);
  k_head<<<dim3((NCLS + 255) / 256, BSZ), dim3(256), 0, stream>>>(pooled,
                                                                  protos, x2v,
                                                                  out);
}